// Round 12
// baseline (558.762 us; speedup 1.0000x reference)
//
#include <hip/hip_runtime.h>
#include <math.h>

#define S_LEN 2048
#define D_DIM 1024
#define B_BATCH 8
#define R_ROWS (B_BATCH * S_LEN)    // 16384
#define BD_ROWS (B_BATCH * D_DIM)   // 8192
#define PAD_ROWS 2050               // 1 zero row + 2048 + 1 zero row per batch

typedef unsigned short u16;
typedef unsigned int u32;
typedef __attribute__((ext_vector_type(8))) short bf16x8;
typedef __attribute__((ext_vector_type(4))) float f32x4;

__device__ __forceinline__ u16 f2bf(float f) {
    u32 x = __float_as_uint(f);
    u32 r = (x + 0x7fffu + ((x >> 16) & 1u)) >> 16;   // RNE
    return (u16)r;
}
__device__ __forceinline__ float bf2f(u16 u) {
    return __uint_as_float(((u32)u) << 16);
}
__device__ __forceinline__ float gelu_exact(float x) {
    return 0.5f * x * (1.0f + erff(x * 0.70710678118654752f));
}
// base-4 digit reverse of a 10-bit index
__device__ __forceinline__ int dr4(int v) {
    v = __brev((unsigned)v) >> 22;
    return ((v & 0x155) << 1) | ((v >> 1) & 0x155);
}
#define PIDX(i) ((i) + ((i) >> 5))   // LDS pad: +1 float per 32

#define GLDS(gsrc, ldst)                                                                   \
    __builtin_amdgcn_global_load_lds(                                                      \
        (const __attribute__((address_space(1))) u32*)(gsrc),                              \
        (__attribute__((address_space(3))) u32*)(ldst), 16, 0, 0)

#define WAIT_LGKM0 do { asm volatile("s_waitcnt lgkmcnt(0)" ::: "memory");                 \
                        __builtin_amdgcn_sched_barrier(0); } while (0)
#define WAIT_VM(n)   do { asm volatile("s_waitcnt vmcnt(" #n ")" ::: "memory");            \
                          __builtin_amdgcn_sched_barrier(0); } while (0)

// ----------------------------------------------------------- zero pad rows
__global__ __launch_bounds__(256) void zero_pads(u16* __restrict__ P0, u16* __restrict__ P1)
{
    const int bid = blockIdx.x;          // 0..31
    u16* P = (bid >= 16) ? P1 : P0;
    const int ridx = bid & 15;
    const int b = ridx >> 1;
    const size_t row = (size_t)b * PAD_ROWS + (size_t)(ridx & 1) * (PAD_ROWS - 1);
    ((uint2*)(P + row * D_DIM))[threadIdx.x] = make_uint2(0u, 0u);
}

// ------------------- merged weight prep: all transposes + WTI in one launch
// z 0-2: conv1 taps -> slots 0-2; z 3-5: conv2 taps -> slots 3-5; z 6: proj ->
// slot 6; z 7: ph interleave -> slots 7-8 (WTI[2n][k]=W[k][n], WTI[2n+1]=*g[k])
__global__ __launch_bounds__(256) void wprep(
    const float* __restrict__ c1, const float* __restrict__ c2,
    const float* __restrict__ pj, const float* __restrict__ ph,
    const float* __restrict__ g, u16* __restrict__ WT)
{
    __shared__ float t[32][33];
    const int z = blockIdx.z;
    const int n0 = blockIdx.x * 32, k0 = blockIdx.y * 32;
    const int tx = threadIdx.x, ty = threadIdx.y;
    const float* src;
    if (z < 3)      src = c1 + (size_t)z * D_DIM * D_DIM;
    else if (z < 6) src = c2 + (size_t)(z - 3) * D_DIM * D_DIM;
    else if (z == 6) src = pj;
    else            src = ph;
#pragma unroll
    for (int u = 0; u < 4; u++)
        t[ty + u * 8][tx] = src[(size_t)(k0 + ty + u * 8) * D_DIM + n0 + tx];
    __syncthreads();
    if (z < 7) {
        u16* op = WT + (size_t)z * D_DIM * D_DIM;
#pragma unroll
        for (int u = 0; u < 4; u++)
            op[(size_t)(n0 + ty + u * 8) * D_DIM + k0 + tx] = f2bf(t[tx][ty + u * 8]);
    } else {
        u16* WTI = WT + 7u * (1u << 20);
        const float gk = g[k0 + tx];
#pragma unroll
        for (int u = 0; u < 4; u++) {
            const int n = n0 + ty + u * 8;
            const float w = t[tx][ty + u * 8];
            WTI[((size_t)(2 * n) << 10) + k0 + tx] = f2bf(w);
            WTI[((size_t)(2 * n + 1) << 10) + k0 + tx] = f2bf(w * gk);
        }
    }
}

// -------- vg[n] = sum_k WTI[2n+1][k]; c0[n] = sum_k lnb[k]*WTI[2n][k] + phb[n]
__global__ __launch_bounds__(256) void gemv_ph(
    const u16* __restrict__ WTI, const float* __restrict__ lnb,
    const float* __restrict__ phb, float* __restrict__ vg, float* __restrict__ c0)
{
    const int wid = threadIdx.x >> 6, lane = threadIdx.x & 63;
    const int n = blockIdx.x * 4 + wid;   // grid 256
    const u16* r0 = WTI + ((size_t)(2 * n) << 10) + lane * 16;
    const u16* r1 = WTI + ((size_t)(2 * n + 1) << 10) + lane * 16;
    float sb = 0.f, sg = 0.f;
#pragma unroll
    for (int h = 0; h < 2; h++) {
        uint4 w0 = *(const uint4*)(r0 + h * 8);
        uint4 w1 = *(const uint4*)(r1 + h * 8);
        float a[8], b8[8];
        a[0] = bf2f((u16)(w0.x & 0xffff)); a[1] = bf2f((u16)(w0.x >> 16));
        a[2] = bf2f((u16)(w0.y & 0xffff)); a[3] = bf2f((u16)(w0.y >> 16));
        a[4] = bf2f((u16)(w0.z & 0xffff)); a[5] = bf2f((u16)(w0.z >> 16));
        a[6] = bf2f((u16)(w0.w & 0xffff)); a[7] = bf2f((u16)(w0.w >> 16));
        b8[0] = bf2f((u16)(w1.x & 0xffff)); b8[1] = bf2f((u16)(w1.x >> 16));
        b8[2] = bf2f((u16)(w1.y & 0xffff)); b8[3] = bf2f((u16)(w1.y >> 16));
        b8[4] = bf2f((u16)(w1.z & 0xffff)); b8[5] = bf2f((u16)(w1.z >> 16));
        b8[6] = bf2f((u16)(w1.w & 0xffff)); b8[7] = bf2f((u16)(w1.w >> 16));
        const int kb = lane * 16 + h * 8;
        float4 l0 = *(const float4*)(lnb + kb), l1 = *(const float4*)(lnb + kb + 4);
        sb += a[0]*l0.x + a[1]*l0.y + a[2]*l0.z + a[3]*l0.w
            + a[4]*l1.x + a[5]*l1.y + a[6]*l1.z + a[7]*l1.w;
        sg += b8[0] + b8[1] + b8[2] + b8[3] + b8[4] + b8[5] + b8[6] + b8[7];
    }
#pragma unroll
    for (int off = 32; off > 0; off >>= 1) {
        sg += __shfl_xor(sg, off);
        sb += __shfl_xor(sb, off);
    }
    if (lane == 0) { vg[n] = sg; c0[n] = sb + phb[n]; }
}

// ---------------------------------------------------------------- embedding
__global__ __launch_bounds__(256) void emb_kernel(
    const int* __restrict__ x, const float* __restrict__ tok,
    const float* __restrict__ pos, u16* __restrict__ P0)
{
    const int row = blockIdx.x;          // b*S + s
    const int tid = threadIdx.x;
    const int t = x[row];
    const int s = row & (S_LEN - 1);
    const int b = row >> 11;
    float4 a = ((const float4*)(tok + (size_t)t * D_DIM))[tid];
    float4 p = ((const float4*)(pos + (size_t)s * D_DIM))[tid];
    uint2 v;
    v.x = (u32)f2bf(a.x + p.x) | ((u32)f2bf(a.y + p.y) << 16);
    v.y = (u32)f2bf(a.z + p.z) | ((u32)f2bf(a.w + p.w) << 16);
    ((uint2*)(P0 + ((size_t)b * PAD_ROWS + 1 + s) * D_DIM))[tid] = v;
}

// ======== conv GEMM: 256x128, BK=32, 8 waves, triple-buffered 72KB LDS =======
// 2 blocks/CU (LDS 144KB, <=128 regs via launch_bounds(512,4)). Conflict-free
// chunk swizzle identical to verified gemm_8ph. Stage targets a buffer whose
// last reader finished 2 barriers earlier; vmcnt(3) keeps 1 tile in flight.
__global__ __launch_bounds__(512, 4) void gemm_c2(
    const u16* __restrict__ A, const u16* __restrict__ WT,
    const float* __restrict__ bias, u16* __restrict__ outB,
    float* __restrict__ rowS, float* __restrict__ rowQ,
    int outBPadded)
{
    __shared__ u16 As[3][8192];   // 256 rows x 32 k
    __shared__ u16 Bs[3][4096];   // 128 cols x 32 k
    const int tid = threadIdx.x;
    const int wid = tid >> 6, lane = tid & 63;
    const int wm = wid >> 1, wn = wid & 1;
    const int l15 = lane & 15, l4 = lane >> 4;
    // grid (8,64): XCD-bijective; each XCD owns 8 contiguous row-panels
    const int flat = blockIdx.y * 8 + blockIdx.x;
    const int xcd = flat & 7;
    const int ii = flat >> 3;          // 0..63
    const int by = xcd * 8 + (ii >> 3);
    const int bx = ii & 7;
    const int row0 = by * 256;
    const int col0 = bx * 128;
    const int b = row0 >> 11;
    const int srow0 = row0 & (S_LEN - 1);
    const int nt = 96;                 // 3 taps x 32 K-tiles of 32

    const int stR = tid >> 2;
    const int stKc = (((tid & 3) ^ ((tid >> 3) & 3)) << 3);
    const int ldsOff = tid * 16;
    const int swz4 = ((l4 ^ ((l15 >> 1) & 3)) << 4);

#define C2_SA(T_, B_) do {                                                                 \
        const int tap_ = (T_) >> 5;                                                        \
        const int kb_ = ((T_) & 31) * 32 + stKc;                                           \
        const size_t ar_ = (size_t)(b * PAD_ROWS + srow0 + tap_);                          \
        GLDS(A + ((ar_ + stR) << 10) + kb_, (char*)&As[B_][0] + ldsOff);                   \
        GLDS(A + ((ar_ + stR + 128) << 10) + kb_, (char*)&As[B_][0] + ldsOff + 8192);      \
    } while (0)
#define C2_SB(T_, B_) do {                                                                 \
        const int tap_ = (T_) >> 5;                                                        \
        const int kb_ = ((T_) & 31) * 32 + stKc;                                           \
        GLDS(WT + ((size_t)tap_ << 20) + ((size_t)(col0 + stR) << 10) + kb_,               \
             (char*)&Bs[B_][0] + ldsOff);                                                  \
    } while (0)
#define C2_RA(B_) do {                                                                     \
        const char* p_ = (const char*)&As[B_][0] + (size_t)(wm * 64 + l15) * 64 + swz4;    \
        a[0] = *(const bf16x8*)(p_);                                                       \
        a[1] = *(const bf16x8*)(p_ + 1024);                                                \
        a[2] = *(const bf16x8*)(p_ + 2048);                                                \
        a[3] = *(const bf16x8*)(p_ + 3072);                                                \
    } while (0)
#define C2_RB(B_) do {                                                                     \
        const char* p_ = (const char*)&Bs[B_][0] + (size_t)(wn * 64 + l15) * 64 + swz4;    \
        bv[0] = *(const bf16x8*)(p_);                                                      \
        bv[1] = *(const bf16x8*)(p_ + 1024);                                               \
        bv[2] = *(const bf16x8*)(p_ + 2048);                                               \
        bv[3] = *(const bf16x8*)(p_ + 3072);                                               \
    } while (0)
#define C2_MF do {                                                                         \
        __builtin_amdgcn_s_setprio(1);                                                     \
        _Pragma("unroll")                                                                  \
        for (int mi_ = 0; mi_ < 4; mi_++)                                                  \
            _Pragma("unroll")                                                              \
            for (int ni_ = 0; ni_ < 4; ni_++)                                              \
                acc[mi_][ni_] = __builtin_amdgcn_mfma_f32_16x16x32_bf16(                   \
                    a[mi_], bv[ni_], acc[mi_][ni_], 0, 0, 0);                              \
        __builtin_amdgcn_s_setprio(0);                                                     \
    } while (0)
#define C2_BAR __builtin_amdgcn_s_barrier()
#define C2_SUB(TT_, RB_, SB_) do {                                                         \
        C2_RA(RB_); C2_RB(RB_);                                                            \
        if ((TT_) + 2 < nt) { C2_SA((TT_) + 2, SB_); C2_SB((TT_) + 2, SB_); }              \
        C2_BAR; WAIT_LGKM0;                                                                \
        C2_MF;                                                                             \
        if ((TT_) + 2 < nt) { WAIT_VM(3); } else { WAIT_VM(0); }                           \
        C2_BAR;                                                                            \
    } while (0)

    f32x4 acc[4][4];
#pragma unroll
    for (int m = 0; m < 4; m++)
#pragma unroll
        for (int n = 0; n < 4; n++) acc[m][n] = (f32x4){0.f, 0.f, 0.f, 0.f};

    bf16x8 a[4], bv[4];
    // prologue: tiles 0,1 staged into bufs 0,1; gate leaves tile 1 in flight
    C2_SA(0, 0); C2_SB(0, 0);
    C2_SA(1, 1); C2_SB(1, 1);
    WAIT_VM(3);
    C2_BAR;

    for (int t = 0; t < nt; t += 3) {
        C2_SUB(t,     0, 2);
        C2_SUB(t + 1, 1, 0);
        C2_SUB(t + 2, 2, 1);
    }
#undef C2_SA
#undef C2_SB
#undef C2_RA
#undef C2_RB
#undef C2_MF
#undef C2_BAR
#undef C2_SUB

    float bb[4];
#pragma unroll
    for (int ni = 0; ni < 4; ni++) bb[ni] = bias[col0 + wn * 64 + ni * 16 + l15];

#pragma unroll
    for (int mi = 0; mi < 4; mi++) {
#pragma unroll
        for (int reg = 0; reg < 4; reg++) {
            const int row = row0 + wm * 64 + mi * 16 + l4 * 4 + reg;
            float s_ = 0.f, q_ = 0.f;
#pragma unroll
            for (int ni = 0; ni < 4; ni++) {
                const int col = col0 + wn * 64 + ni * 16 + l15;
                float v = gelu_exact(acc[mi][ni][reg] + bb[ni]);
                const size_t orow = outBPadded
                    ? ((size_t)(row >> 11) * PAD_ROWS + 1 + (size_t)(row & (S_LEN - 1)))
                    : (size_t)row;
                outB[orow * D_DIM + col] = f2bf(v);
                if (rowS) { s_ += v; q_ = fmaf(v, v, q_); }
            }
            if (rowS) {
#pragma unroll
                for (int off = 1; off < 16; off <<= 1) {
                    s_ += __shfl_xor(s_, off);
                    q_ += __shfl_xor(q_, off);
                }
                if (l15 == 0) {
                    atomicAdd(&rowS[row], s_);
                    atomicAdd(&rowQ[row], q_);
                }
            }
        }
    }
}

// ============ 256x256 BK=64 8-wave, 8-phase counted-vmcnt MFMA GEMM ==========
// (verified: SQ_LDS_BANK_CONFLICT = 0) — used for proj; macros shared with
// phstats_8ph below.
__global__ __launch_bounds__(512, 2) void gemm_8ph(
    const u16* __restrict__ A, const u16* __restrict__ WT,
    const float* __restrict__ bias,
    u16* __restrict__ outB,
    float* __restrict__ rowS, float* __restrict__ rowQ)
{
    __shared__ u16 As[2][2][8192];    // [dbuf][ks-half][256 rows x 32 k]
    __shared__ u16 Bs[2][2][8192];    // [dbuf][ks-half][256 cols x 32 k]
    const int tid = threadIdx.x;
    const int wid = tid >> 6, lane = tid & 63;
    const int wm = wid >> 2, wn = wid & 3;
    const int l15 = lane & 15, l4 = lane >> 4;
    // grid (4,64): XCD-bijective swizzle
    const int flat = blockIdx.y * 4 + blockIdx.x;
    const int xcd = flat & 7;
    const int ii = flat >> 3;          // 0..31
    const int by = xcd * 8 + (ii >> 2);
    const int bx = ii & 3;
    const int row0 = by * 256;
    const int col0 = bx * 256;
    const int NI = 8;                  // K=1024

    const int stR = tid >> 2;
    const int stKc = (((tid & 3) ^ ((tid >> 3) & 3)) << 3);
    const int ldsOff = tid * 16;
    const int swz4 = ((l4 ^ ((l15 >> 1) & 3)) << 4);

#define STAGE_A(T_, s_) do {                                                               \
        const int kb_ = ((T_) & 15) * 64 + (s_) * 32 + stKc;                               \
        GLDS(A + (((size_t)row0 + stR) << 10) + kb_,                                       \
             (char*)&As[(T_) & 1][s_][0] + ldsOff);                                        \
        GLDS(A + (((size_t)row0 + stR + 128) << 10) + kb_,                                 \
             (char*)&As[(T_) & 1][s_][0] + ldsOff + 8192);                                 \
    } while (0)
#define STAGE_B(T_, s_) do {                                                               \
        const int kb_ = ((T_) & 15) * 64 + (s_) * 32 + stKc;                               \
        const u16* wp_ = WT + ((size_t)(col0 + stR) << 10) + kb_;                          \
        GLDS(wp_, (char*)&Bs[(T_) & 1][s_][0] + ldsOff);                                   \
        GLDS(wp_ + (size_t)(128 << 10), (char*)&Bs[(T_) & 1][s_][0] + ldsOff + 8192);      \
    } while (0)
#define RD_A(dst_, buf_, s_, mih_) do {                                                    \
        const char* p_ = (const char*)&As[buf_][s_][0]                                     \
                         + (size_t)(wm * 128 + (mih_) * 64 + l15) * 64 + swz4;             \
        dst_[0] = *(const bf16x8*)(p_);                                                    \
        dst_[1] = *(const bf16x8*)(p_ + 1024);                                             \
        dst_[2] = *(const bf16x8*)(p_ + 2048);                                             \
        dst_[3] = *(const bf16x8*)(p_ + 3072);                                             \
    } while (0)
#define RD_B(dst_, buf_, s_) do {                                                          \
        const char* p_ = (const char*)&Bs[buf_][s_][0]                                     \
                         + (size_t)(wn * 64 + l15) * 64 + swz4;                            \
        dst_[0] = *(const bf16x8*)(p_);                                                    \
        dst_[1] = *(const bf16x8*)(p_ + 1024);                                             \
        dst_[2] = *(const bf16x8*)(p_ + 2048);                                             \
        dst_[3] = *(const bf16x8*)(p_ + 3072);                                             \
    } while (0)
#define MF(mih_, av_, bv_) do {                                                            \
        __builtin_amdgcn_s_setprio(1);                                                     \
        _Pragma("unroll")                                                                  \
        for (int mi_ = 0; mi_ < 4; mi_++)                                                  \
            _Pragma("unroll")                                                              \
            for (int ni_ = 0; ni_ < 4; ni_++)                                              \
                acc[(mih_) * 4 + mi_][ni_] = __builtin_amdgcn_mfma_f32_16x16x32_bf16(      \
                    av_[mi_], bv_[ni_], acc[(mih_) * 4 + mi_][ni_], 0, 0, 0);              \
        __builtin_amdgcn_s_setprio(0);                                                     \
    } while (0)
#define BAR __builtin_amdgcn_s_barrier()
#define LOOP8PH                                                                            \
    for (int i = 0; i < NI; ++i) {                                                         \
        const int o = 2 * i + 1;                                                           \
        const int e2 = 2 * i + 2, o2 = 2 * i + 3;                                          \
        const bool last = (i == NI - 1);                                                   \
        bf16x8 a[4], bv[4];                                                                \
        RD_A(a, 0, 0, 0); RD_B(bv, 0, 0);                                                  \
        STAGE_A(o, 1);                                                                     \
        BAR; WAIT_LGKM0;                                                                   \
        MF(0, a, bv);                                                                      \
        BAR;                                                                               \
        RD_A(a, 0, 0, 1);                                                                  \
        STAGE_B(o, 1);                                                                     \
        BAR; WAIT_LGKM0;                                                                   \
        MF(1, a, bv);                                                                      \
        BAR;                                                                               \
        RD_A(a, 0, 1, 0); RD_B(bv, 0, 1);                                                  \
        if (!last) STAGE_A(e2, 0);                                                         \
        BAR; WAIT_LGKM0;                                                                   \
        MF(0, a, bv);                                                                      \
        BAR;                                                                               \
        RD_A(a, 0, 1, 1);                                                                  \
        if (!last) STAGE_B(e2, 0);                                                         \
        BAR; WAIT_LGKM0;                                                                   \
        MF(1, a, bv);                                                                      \
        if (last) { WAIT_VM(0); } else { WAIT_VM(4); }                                     \
        BAR;                                                                               \
        RD_A(a, 1, 0, 0); RD_B(bv, 1, 0);                                                  \
        if (!last) STAGE_A(e2, 1);                                                         \
        BAR; WAIT_LGKM0;                                                                   \
        MF(0, a, bv);                                                                      \
        BAR;                                                                               \
        RD_A(a, 1, 0, 1);                                                                  \
        if (!last) STAGE_B(e2, 1);                                                         \
        BAR; WAIT_LGKM0;                                                                   \
        MF(1, a, bv);                                                                      \
        BAR;                                                                               \
        RD_A(a, 1, 1, 0); RD_B(bv, 1, 1);                                                  \
        if (!last) STAGE_A(o2, 0);                                                         \
        BAR; WAIT_LGKM0;                                                                   \
        MF(0, a, bv);                                                                      \
        BAR;                                                                               \
        RD_A(a, 1, 1, 1);                                                                  \
        if (!last) STAGE_B(o2, 0);                                                         \
        BAR; WAIT_LGKM0;                                                                   \
        MF(1, a, bv);                                                                      \
        if (!last) { WAIT_VM(4); }                                                         \
        BAR;                                                                               \
    }

    f32x4 acc[8][4];
#pragma unroll
    for (int m = 0; m < 8; m++)
#pragma unroll
        for (int n = 0; n < 4; n++) acc[m][n] = (f32x4){0.f, 0.f, 0.f, 0.f};

    STAGE_A(0, 0); STAGE_B(0, 0);
    STAGE_A(0, 1); STAGE_B(0, 1);
    STAGE_A(1, 0); STAGE_B(1, 0);
    WAIT_VM(4);
    BAR;
    LOOP8PH

    float bb[4];
#pragma unroll
    for (int ni = 0; ni < 4; ni++) bb[ni] = bias[col0 + wn * 64 + ni * 16 + l15];

#pragma unroll
    for (int mi = 0; mi < 8; mi++) {
#pragma unroll
        for (int reg = 0; reg < 4; reg++) {
            const int row = row0 + wm * 128 + mi * 16 + l4 * 4 + reg;
            float s_ = 0.f, q_ = 0.f;
#pragma unroll
            for (int ni = 0; ni < 4; ni++) {
                const int col = col0 + wn * 64 + ni * 16 + l15;
                float v = acc[mi][ni][reg] + bb[ni];
                outB[(size_t)row * D_DIM + col] = f2bf(v);
                s_ += v; q_ = fmaf(v, v, q_);
            }
#pragma unroll
            for (int off = 1; off < 16; off <<= 1) {
                s_ += __shfl_xor(s_, off);
                q_ += __shfl_xor(q_, off);
            }
            if (l15 == 0) {
                atomicAdd(&rowS[row], s_);
                atomicAdd(&rowQ[row], q_);
            }
        }
    }
}

// ====== ph-stats via interleaved-B 8-phase GEMM, MASKED rows only ======
__global__ __launch_bounds__(512, 2) void phstats_8ph(
    const u16* __restrict__ A, const u16* __restrict__ WT,
    const float* __restrict__ phb, const float* __restrict__ vg,
    const float* __restrict__ c0,
    const float* __restrict__ rowS2, const float* __restrict__ rowQ2,
    const int* __restrict__ Ndev,
    float* __restrict__ Sxx, float* __restrict__ Stt, float* __restrict__ Sxt)
{
    __shared__ u16 As[2][2][8192];
    __shared__ u16 Bs[2][2][8192];
    const int tid = threadIdx.x;
    const int wid = tid >> 6, lane = tid & 63;
    const int wm = wid >> 2, wn = wid & 3;
    const int l15 = lane & 15, l4 = lane >> 4;
    // grid (8,32): 256 blocks; XCD-bijective
    const int flat = blockIdx.y * 8 + blockIdx.x;
    const int xcd = flat & 7;
    const int ii = flat >> 3;          // 0..31
    const int by = xcd * 4 + (ii >> 3);   // 0..31 row-blocks
    const int bx = ii & 7;                // 0..7 col-blocks
    const int batch = by >> 2;
    const int rb = by & 3;
    if (rb * 256 >= Ndev[batch]) return;
    const int row0 = batch * S_LEN + rb * 256;
    const int col0 = bx * 256;         // of 2048
    const int NI = 8;

    const int stR = tid >> 2;
    const int stKc = (((tid & 3) ^ ((tid >> 3) & 3)) << 3);
    const int ldsOff = tid * 16;
    const int swz4 = ((l4 ^ ((l15 >> 1) & 3)) << 4);

    f32x4 acc[8][4];
#pragma unroll
    for (int m = 0; m < 8; m++)
#pragma unroll
        for (int n = 0; n < 4; n++) acc[m][n] = (f32x4){0.f, 0.f, 0.f, 0.f};

    STAGE_A(0, 0); STAGE_B(0, 0);
    STAGE_A(0, 1); STAGE_B(0, 1);
    STAGE_A(1, 0); STAGE_B(1, 0);
    WAIT_VM(4);
    BAR;
    LOOP8PH
#undef STAGE_A
#undef STAGE_B
#undef RD_A
#undef RD_B
#undef MF
#undef BAR
#undef LOOP8PH

    float phv[4], vgv[4], c0v[4];
#pragma unroll
    for (int ni = 0; ni < 4; ni++) {
        const int col = col0 + wn * 64 + ni * 16 + l15;
        const int j = col >> 1;
        phv[ni] = phb[j]; vgv[ni] = vg[j]; c0v[ni] = c0[j];
    }
    const bool odd = (l15 & 1) != 0;
#pragma unroll
    for (int mi = 0; mi < 8; mi++) {
#pragma unroll
        for (int reg = 0; reg < 4; reg++) {
            const int row = row0 + wm * 128 + mi * 16 + l4 * 4 + reg;
            const float mS = rowS2[row] * (1.0f / D_DIM);
            const float var = rowQ2[row] * (1.0f / D_DIM) - mS * mS;
            const float rsv = rsqrtf(var + 1e-5f);
            const float mrs = mS * rsv;
            float sxx = 0.f, stt = 0.f, sxt = 0.f;
#pragma unroll
            for (int ni = 0; ni < 4; ni++) {
                const float raw = acc[mi][ni][reg];
                const float val = odd ? (rsv * raw - mrs * vgv[ni] + c0v[ni])
                                      : (raw + phv[ni]);
                const float par = __shfl_xor(val, 1);
                const float pt = odd ? par : val;
                const float px = odd ? val : par;
                stt = fmaf(pt, pt, stt);
                sxx = fmaf(px, px, sxx);
                sxt = fmaf(pt, px, sxt);
            }
#pragma unroll
            for (int off = 1; off < 16; off <<= 1) {
                sxx += __shfl_xor(sxx, off);
                stt += __shfl_xor(stt, off);
                sxt += __shfl_xor(sxt, off);
            }
            if (l15 == 0) {
                atomicAdd(&Sxx[row], 0.5f * sxx);
                atomicAdd(&Stt[row], 0.5f * stt);
                atomicAdd(&Sxt[row], 0.5f * sxt);
            }
        }
    }
}

// ------- fused LN + transpose: bf16 [B,S,D] -> bf16 [B,D,S]; stats from rowS/rowQ
__global__ __launch_bounds__(256) void transposeLN(
    const u16* __restrict__ in, const float* __restrict__ rowS,
    const float* __restrict__ rowQ,
    const float* __restrict__ g, const float* __restrict__ beta,
    u16* __restrict__ out)
{
    __shared__ float t[32][33];
    const int b = blockIdx.z;
    const int n0 = blockIdx.x * 32, m0 = blockIdx.y * 32;   // n=d, m=s
    const int tx = threadIdx.x, ty = threadIdx.y;
    const u16* ip = in + (size_t)b * S_LEN * D_DIM;
    u16* op = out + (size_t)b * S_LEN * D_DIM;
#pragma unroll
    for (int u = 0; u < 4; u++)
        t[ty + u * 8][tx] = bf2f(ip[(size_t)(m0 + ty + u * 8) * D_DIM + n0 + tx]);
    __syncthreads();
    const int row = b * S_LEN + m0 + tx;
    const float mS = rowS[row] * (1.0f / D_DIM);
    const float var = rowQ[row] * (1.0f / D_DIM) - mS * mS;
    const float rs = rsqrtf(var + 1e-5f);
#pragma unroll
    for (int u = 0; u < 4; u++) {
        const int d = n0 + ty + u * 8;
        const float val = (t[tx][ty + u * 8] - mS) * rs * g[d] + beta[d];
        op[(size_t)d * S_LEN + m0 + tx] = f2bf(val);
    }
}

// --------------------- forward real-FFT: 2048-pt via 1024-pt radix-4 packing
// input bf16 [B,D,S]; spectrum stored as packed bf16 pairs.
__global__ __launch_bounds__(256) void fft_fwd(
    const u16* __restrict__ in, u32* __restrict__ X, int* __restrict__ counts)
{
    __shared__ float re[1056], im[1056], twr[1024], twi[1024];
    __shared__ float redf[4];
    __shared__ int redi[4];
    const int tid = threadIdx.x;
    const int row = blockIdx.x;          // b*D + d
    const u32* src = (const u32*)(in + (size_t)row * S_LEN);
#pragma unroll
    for (int u = 0; u < 4; u++) {
        int e = tid + u * 256;
        float ang = -3.14159265358979f * (float)e * (1.0f / 512.0f);
        float sn, cs; __sincosf(ang, &sn, &cs);
        twr[e] = cs; twi[e] = sn;
    }
#pragma unroll
    for (int u = 0; u < 4; u++) {
        int t = tid + u * 256;
        u32 w = src[t];                  // z[t] = x[2t] + i x[2t+1]
        int p = PIDX(dr4(t));
        re[p] = bf2f((u16)(w & 0xffff)); im[p] = bf2f((u16)(w >> 16));
    }
    __syncthreads();
#pragma unroll
    for (int s = 1; s <= 5; ++s) {
        const int mq = 1 << (2 * (s - 1));
        const int fsh = 2 * (5 - s);
        const int j = tid & (mq - 1);
        const int g = tid >> (2 * (s - 1));
        const int i0 = (g << (2 * s)) + j;
        const int e1 = j << fsh;
        const int p0 = PIDX(i0), p1 = PIDX(i0 + mq), p2 = PIDX(i0 + 2 * mq), p3 = PIDX(i0 + 3 * mq);
        float a0r = re[p0], a0i = im[p0];
        float a1r = re[p1], a1i = im[p1];
        float a2r = re[p2], a2i = im[p2];
        float a3r = re[p3], a3i = im[p3];
        float w1r = twr[e1], w1i = twi[e1];
        float w2r = twr[2 * e1], w2i = twi[2 * e1];
        float w3r = twr[3 * e1], w3i = twi[3 * e1];
        float b1r = a1r * w1r - a1i * w1i, b1i = a1r * w1i + a1i * w1r;
        float b2r = a2r * w2r - a2i * w2i, b2i = a2r * w2i + a2i * w2r;
        float b3r = a3r * w3r - a3i * w3i, b3i = a3r * w3i + a3i * w3r;
        float t0r = a0r + b2r, t0i = a0i + b2i;
        float t1r = a0r - b2r, t1i = a0i - b2i;
        float t2r = b1r + b3r, t2i = b1i + b3i;
        float t3r = b1r - b3r, t3i = b1i - b3i;
        re[p0] = t0r + t2r; im[p0] = t0i + t2i;
        re[p2] = t0r - t2r; im[p2] = t0i - t2i;
        re[p1] = t1r + t3i; im[p1] = t1i - t3r;   // t1 - i*t3
        re[p3] = t1r - t3i; im[p3] = t1i + t3r;   // t1 + i*t3
        __syncthreads();
    }
    u32* dst = X + (size_t)row * 1024;
    float mag[4];
    float xtra = 0.0f;
    float lmax = 0.0f;
#pragma unroll
    for (int u = 0; u < 4; u++) {
        int k = tid + u * 256;
        int mk = (1024 - k) & 1023;
        float rk = re[PIDX(k)], ik = im[PIDX(k)];
        float rm = re[PIDX(mk)], imm = im[PIDX(mk)];
        float er = 0.5f * (rk + rm);
        float ei = 0.5f * (ik - imm);
        float orr = 0.5f * (ik + imm);
        float oii = -0.5f * (rk - rm);
        float ang = -3.14159265358979f * (float)k * (1.0f / 1024.0f);
        float sn, cs; __sincosf(ang, &sn, &cs);
        float xr = er + orr * cs - oii * sn;
        float xi = ei + orr * sn + oii * cs;
        dst[k] = (u32)f2bf(xr) | ((u32)f2bf(xi) << 16);
        float m2 = xr * xr + xi * xi;
        mag[u] = m2;
        lmax = fmaxf(lmax, m2);
        if (k == 0) {
            float x1024 = re[PIDX(0)] - im[PIDX(0)];
            xtra = x1024 * x1024;
            lmax = fmaxf(lmax, xtra);
        }
    }
#pragma unroll
    for (int off = 32; off > 0; off >>= 1) lmax = fmaxf(lmax, __shfl_xor(lmax, off));
    if ((tid & 63) == 0) redf[tid >> 6] = lmax;
    __syncthreads();
    const float bmax = fmaxf(fmaxf(redf[0], redf[1]), fmaxf(redf[2], redf[3]));
    const float thr = 0.01f * bmax;
    int lc = 0;
#pragma unroll
    for (int u = 0; u < 4; u++) {
        int k = tid + u * 256;
        lc += (mag[u] > thr) ? ((k == 0) ? 1 : 2) : 0;
    }
    if (tid == 0) lc += (xtra > thr) ? 1 : 0;
#pragma unroll
    for (int off = 32; off > 0; off >>= 1) lc += __shfl_xor(lc, off);
    if ((tid & 63) == 0) redi[tid >> 6] = lc;
    __syncthreads();
    if (tid == 0)
        atomicAdd(&counts[(row >> 10) * 64 + (row & 63)],
                  redi[0] + redi[1] + redi[2] + redi[3]);
}

// ------------------------------------------------------------- N from counts
__global__ void calc_n(const int* __restrict__ counts, int* __restrict__ Ndev)
{
    const int t = threadIdx.x;           // 64 threads
    for (int b = 0; b < B_BATCH; b++) {
        int c = counts[b * 64 + t];
#pragma unroll
        for (int off = 32; off > 0; off >>= 1) c += __shfl_xor(c, off);
        if (t == 0) {
            float cf = (float)c * (1.0f / 2097152.0f);
            float cr = 0.5f * (1.0f - cf);
            cr = fminf(fmaxf(cr, 0.1f), 1.0f);
            int n = (int)(cr * 2048.0f);
            n = n < 1 ? 1 : (n > S_LEN ? S_LEN : n);
            Ndev[b] = n;
        }
    }
}

// --------------------- masked inverse 2048-ifft (real part) -> bf16 [B,D,S]
__global__ __launch_bounds__(256) void fft_inv(
    const u32* __restrict__ X, const int* __restrict__ Ndev,
    u16* __restrict__ outb)
{
    __shared__ float re[1056], im[1056], twr[1024], twi[1024];
    const int tid = threadIdx.x;
    const int row = blockIdx.x;          // b*D + d
    const int Nb = Ndev[row >> 10];
    const u32* src = X + (size_t)row * 1024;
#pragma unroll
    for (int u = 0; u < 4; u++) {
        int e = tid + u * 256;
        float ang = 3.14159265358979f * (float)e * (1.0f / 512.0f);
        float sn, cs; __sincosf(ang, &sn, &cs);
        twr[e] = cs; twi[e] = sn;
    }
#pragma unroll
    for (int u = 0; u < 4; u++) {
        int k = tid + u * 256;
        float Ar = 0.f, Ai = 0.f, Br = 0.f, Bi = 0.f;
        if (k == 0) {
            u32 w = src[0];
            Ar = bf2f((u16)(w & 0xffff)); Ai = bf2f((u16)(w >> 16));
        } else {
            if (k < Nb) {
                u32 w = src[k];
                Ar = 0.5f * bf2f((u16)(w & 0xffff));
                Ai = 0.5f * bf2f((u16)(w >> 16));
            }
            int km = 1024 - k;
            if (km < Nb) {
                u32 w = src[km];
                Br = 0.5f * bf2f((u16)(w & 0xffff));
                Bi = -0.5f * bf2f((u16)(w >> 16));
            }
        }
        float ang = 3.14159265358979f * (float)k * (1.0f / 1024.0f);
        float sn, cs; __sincosf(ang, &sn, &cs);
        float drr = Ar - Br, dri = Ai - Bi;
        float Dr = drr * cs - dri * sn;
        float Di = drr * sn + dri * cs;
        float Cr = (Ar + Br) - Di;
        float Ci = (Ai + Bi) + Dr;
        int p = PIDX(dr4(k));
        re[p] = Cr; im[p] = Ci;
    }
    __syncthreads();
#pragma unroll
    for (int s = 1; s <= 4; ++s) {
        const int mq = 1 << (2 * (s - 1));
        const int fsh = 2 * (5 - s);
        const int j = tid & (mq - 1);
        const int g = tid >> (2 * (s - 1));
        const int i0 = (g << (2 * s)) + j;
        const int e1 = j << fsh;
        const int p0 = PIDX(i0), p1 = PIDX(i0 + mq), p2 = PIDX(i0 + 2 * mq), p3 = PIDX(i0 + 3 * mq);
        float a0r = re[p0], a0i = im[p0];
        float a1r = re[p1], a1i = im[p1];
        float a2r = re[p2], a2i = im[p2];
        float a3r = re[p3], a3i = im[p3];
        float w1r = twr[e1], w1i = twi[e1];
        float w2r = twr[2 * e1], w2i = twi[2 * e1];
        float w3r = twr[3 * e1], w3i = twi[3 * e1];
        float b1r = a1r * w1r - a1i * w1i, b1i = a1r * w1i + a1i * w1r;
        float b2r = a2r * w2r - a2i * w2i, b2i = a2r * w2i + a2i * w2r;
        float b3r = a3r * w3r - a3i * w3i, b3i = a3r * w3i + a3i * w3r;
        float t0r = a0r + b2r, t0i = a0i + b2i;
        float t1r = a0r - b2r, t1i = a0i - b2i;
        float t2r = b1r + b3r, t2i = b1i + b3i;
        float t3r = b1r - b3r, t3i = b1i - b3i;
        re[p0] = t0r + t2r; im[p0] = t0i + t2i;
        re[p2] = t0r - t2r; im[p2] = t0i - t2i;
        re[p1] = t1r - t3i; im[p1] = t1i + t3r;   // t1 + i*t3
        re[p3] = t1r + t3i; im[p3] = t1i - t3r;   // t1 - i*t3
        __syncthreads();
    }
    // stage 5: registers -> global (packed bf16)
    {
        const int j = tid;               // mq = 256
        const int e1 = j;
        const int p0 = PIDX(j), p1 = PIDX(j + 256), p2 = PIDX(j + 512), p3 = PIDX(j + 768);
        float a0r = re[p0], a0i = im[p0];
        float a1r = re[p1], a1i = im[p1];
        float a2r = re[p2], a2i = im[p2];
        float a3r = re[p3], a3i = im[p3];
        float w1r = twr[e1], w1i = twi[e1];
        float w2r = twr[2 * e1], w2i = twi[2 * e1];
        float w3r = twr[3 * e1], w3i = twi[3 * e1];
        float b1r = a1r * w1r - a1i * w1i, b1i = a1r * w1i + a1i * w1r;
        float b2r = a2r * w2r - a2i * w2i, b2i = a2r * w2i + a2i * w2r;
        float b3r = a3r * w3r - a3i * w3i, b3i = a3r * w3i + a3i * w3r;
        float t0r = a0r + b2r, t0i = a0i + b2i;
        float t1r = a0r - b2r, t1i = a0i - b2i;
        float t2r = b1r + b3r, t2i = b1i + b3i;
        float t3r = b1r - b3r, t3i = b1i - b3i;
        const float sc = 1.0f / 2048.0f;
        u32* dst = (u32*)(outb + (size_t)row * S_LEN);
        dst[j]       = (u32)f2bf((t0r + t2r) * sc) | ((u32)f2bf((t0i + t2i) * sc) << 16);
        dst[j + 256] = (u32)f2bf((t1r - t3i) * sc) | ((u32)f2bf((t1i + t3r) * sc) << 16);
        dst[j + 512] = (u32)f2bf((t0r - t2r) * sc) | ((u32)f2bf((t0i - t2i) * sc) << 16);
        dst[j + 768] = (u32)f2bf((t1r + t3i) * sc) | ((u32)f2bf((t1i - t3r) * sc) << 16);
    }
}

// ---------------------- bf16 transpose [B][M][N] -> [B][N][M]
__global__ __launch_bounds__(256) void transpose_bb(
    const u16* __restrict__ in, u16* __restrict__ out, int M, int N)
{
    __shared__ u16 t[32][33];
    const int b = blockIdx.z;
    const int n0 = blockIdx.x * 32, m0 = blockIdx.y * 32;
    const int tx = threadIdx.x, ty = threadIdx.y;
    const u16* ip = in + (size_t)b * M * N;
    u16* op = out + (size_t)b * M * N;
#pragma unroll
    for (int u = 0; u < 4; u++)
        t[ty + u * 8][tx] = ip[(size_t)(m0 + ty + u * 8) * N + n0 + tx];
    __syncthreads();
#pragma unroll
    for (int u = 0; u < 4; u++)
        op[(size_t)(n0 + ty + u * 8) * M + m0 + tx] = t[tx][ty + u * 8];
}

// -------- LN(proj_out bf16) + cos-sim/smooth-L1 row stats; stats precomputed
__global__ __launch_bounds__(256) void ln_loss(
    const u16* __restrict__ in, const float* __restrict__ g,
    const float* __restrict__ beta, float* __restrict__ outF,
    const float* __restrict__ rowS2, const float* __restrict__ rowQ2,
    float* __restrict__ rowA, float* __restrict__ rowL1)
{
    const int row = blockIdx.x;
    const int tid = threadIdx.x;
    uint2 raw = ((const uint2*)(in + (size_t)row * D_DIM))[tid];
    float v0 = bf2f((u16)(raw.x & 0xffff)), v1 = bf2f((u16)(raw.x >> 16));
    float v2 = bf2f((u16)(raw.y & 0xffff)), v3 = bf2f((u16)(raw.y >> 16));
    const float m = rowS2[row] * (1.0f / D_DIM);
    const float var = rowQ2[row] * (1.0f / D_DIM) - m * m;
    const float rs = rsqrtf(var + 1e-5f);
    float4 gg = ((const float4*)g)[tid];
    float4 bb = ((const float4*)beta)[tid];
    float4 o;
    o.x = (v0 - m) * rs * gg.x + bb.x;
    o.y = (v1 - m) * rs * gg.y + bb.y;
    o.z = (v2 - m) * rs * gg.z + bb.z;
    o.w = (v3 - m) * rs * gg.w + bb.w;
    ((float4*)(outF + (size_t)row * D_DIM))[tid] = o;

    float xx = o.x * o.x + o.y * o.y + o.z * o.z + o.w * o.w;
    float rr = v0 * v0 + v1 * v1 + v2 * v2 + v3 * v3;
    float xr = o.x * v0 + o.y * v1 + o.z * v2 + o.w * v3;
    float l1 = 0.f;
    {
        float d, ad;
        d = o.x - v0; ad = fabsf(d); l1 += (ad < 1.0f) ? 0.5f * d * d : ad - 0.5f;
        d = o.y - v1; ad = fabsf(d); l1 += (ad < 1.0f) ? 0.5f * d * d : ad - 0.5f;
        d = o.z - v2; ad = fabsf(d); l1 += (ad < 1.0f) ? 0.5f * d * d : ad - 0.5f;
        d = o.w - v3; ad = fabsf(d); l1 += (ad < 1.0f) ? 0.5f * d * d : ad - 0.5f;
    }
#pragma unroll
    for (int off = 32; off > 0; off >>= 1) {
        xx += __shfl_xor(xx, off); rr += __shfl_xor(rr, off);
        xr += __shfl_xor(xr, off); l1 += __shfl_xor(l1, off);
    }
    __shared__ float red2[4][4];
    if ((tid & 63) == 0) {
        int w = tid >> 6;
        red2[w][0] = xx; red2[w][1] = rr; red2[w][2] = xr; red2[w][3] = l1;
    }
    __syncthreads();
    if (tid == 0) {
        xx = red2[0][0] + red2[1][0] + red2[2][0] + red2[3][0];
        rr = red2[0][1] + red2[1][1] + red2[2][1] + red2[3][1];
        xr = red2[0][2] + red2[1][2] + red2[2][2] + red2[3][2];
        l1 = red2[0][3] + red2[1][3] + red2[2][3] + red2[3][3];
        float nx = fmaxf(sqrtf(xx), 1e-12f);
        float nr = fmaxf(sqrtf(rr), 1e-12f);
        float cs = xr / (nx * nr);
        cs = fminf(fmaxf(cs, -1.0f + 1e-8f), 1.0f - 1e-8f);
        rowA[row] = 1.0f - cs;
        rowL1[row] = l1;
    }
}

// ------------------------------------------------------------- final loss
__global__ __launch_bounds__(1024) void final_loss(
    const float* __restrict__ rowA, const float* __restrict__ rowL1,
    const float* __restrict__ Sxx, const float* __restrict__ Stt,
    const float* __restrict__ Sxt,
    const int* __restrict__ Ndev, float* __restrict__ out)
{
    const int tid = threadIdx.x;
    float sa = 0.f, sb = 0.f;
#pragma unroll
    for (int i = 0; i < 16; i++) {
        int r = tid + i * 1024;
        sa += rowA[r];
        int b = r >> 11, s = r & (S_LEN - 1);
        if (s < Ndev[b]) {
            float sx = Sxx[r], st = Stt[r], sxtv = Sxt[r];
            float nxx = fmaxf(sqrtf(sx), 1e-12f);
            float ntt = fmaxf(sqrtf(st), 1e-12f);
            float sem = (sx / (nxx * nxx) + st / (ntt * ntt)
                         - 2.0f * sxtv / (nxx * ntt)) * (1.0f / D_DIM);
            sb += 0.2f * (rowL1[r] * (1.0f / D_DIM)) + 0.2f * sem;
        }
    }
#pragma unroll
    for (int off = 32; off > 0; off >>= 1) {
        sa += __shfl_xor(sa, off);
        sb += __shfl_xor(sb, off);
    }
    __shared__ float ra[16], rb[16];
    if ((tid & 63) == 0) { ra[tid >> 6] = sa; rb[tid >> 6] = sb; }
    __syncthreads();
    if (tid == 0) {
        float A = 0.f, Bs = 0.f;
#pragma unroll
        for (int i = 0; i < 16; i++) { A += ra[i]; Bs += rb[i]; }
        int K = 0;
        for (int b = 0; b < B_BATCH; b++) K += Ndev[b];
        float Kf = (float)K;
        float M = A * (1.0f / 16384.0f);
        out[(size_t)R_ROWS * D_DIM] = (0.6f * M * Kf + Bs) / (Kf + 1e-8f);
    }
}

// ---------------------------------------------------------------------------
extern "C" void kernel_launch(void* const* d_in, const int* in_sizes, int n_in,
                              void* d_out, int out_size, void* d_ws, size_t ws_size,
                              hipStream_t stream)
{
    (void)in_sizes; (void)n_in; (void)out_size; (void)ws_size;
    const int*   x       = (const int*)  d_in[0];
    const float* tok     = (const float*)d_in[1];
    const float* pos     = (const float*)d_in[2];
    const float* conv1_w = (const float*)d_in[3];
    const float* conv1_b = (const float*)d_in[4];
    const float* conv2_w = (const float*)d_in[5];
    const float* conv2_b = (const float*)d_in[6];
    const float* proj_w  = (const float*)d_in[7];
    const float* proj_b  = (const float*)d_in[8];
    const float* ph_w    = (const float*)d_in[9];
    const float* ph_b    = (const float*)d_in[10];
    const float* ln_g    = (const float*)d_in[11];
    const float* ln_b    = (const float*)d_in[12];
    float* out = (float*)d_out;

    char* ws = (char*)d_ws;
    int*    counts = (int*)(ws);                         // 512 ints
    int*    Ndev   = (int*)(ws + 2048);
    float*  Sxx    = (float*)(ws + 266240);
    float*  Stt    = (float*)(ws + 331776);
    float*  Sxt    = (float*)(ws + 397312);
    float*  rowA   = (float*)(ws + 462848);
    float*  rowL1  = (float*)(ws + 528384);
    float*  vg     = (float*)(ws + 593920);
    float*  c0     = (float*)(ws + 598016);
    float*  rowS   = (float*)(ws + 602112);              // conv2 row sums
    float*  rowQ   = (float*)(ws + 667648);
    float*  rowS2  = (float*)(ws + 733184);              // proj row sums
    float*  rowQ2  = (float*)(ws + 798720);              // ends 864256 < 1MB
    const size_t MB = 1ull << 20;
    u16*   WT   = (u16*)(ws + 1 * MB);      // 9 slots x 2MB (7-8 = WTI)
    u16*   WTI  = WT + 7u * (1u << 20);
    u16*   P0   = (u16*)(ws + 19 * MB);     // 32.03 MB padded bf16 activations
    u16*   P1   = (u16*)(ws + 52 * MB);     // 32.03 MB
    u32*   Xs   = (u32*)(ws + 85 * MB);     // 32 MiB packed-bf16 spectrum
    u16*   BTR  = (u16*)(ws + 118 * MB);    // 32 MiB LN'd bf16 [B,D,S]

    hipMemsetAsync(ws, 0, MB, stream);
    zero_pads<<<32, 256, 0, stream>>>(P0, P1);
    wprep<<<dim3(32, 32, 8), dim3(32, 8), 0, stream>>>(conv1_w, conv2_w, proj_w,
                                                       ph_w, ln_g, WT);
    gemv_ph<<<256, 256, 0, stream>>>(WTI, ln_b, ph_b, vg, c0);
    // h0 (padded bf16)
    emb_kernel<<<R_ROWS, 256, 0, stream>>>(x, tok, pos, P0);
    // h1 = gelu(conv1(h0)) -> P1 padded
    gemm_c2<<<dim3(8, 64), 512, 0, stream>>>(P0, WT, conv1_b, P1,
                                             nullptr, nullptr, 1);
    // h2 = gelu(conv2(h1)) -> P0 flat + row LN-stats atomics
    gemm_c2<<<dim3(8, 64), 512, 0, stream>>>(P1, WT + 3u * (1u << 20), conv2_b, P0,
                                             rowS, rowQ, 0);
    // fused LN-transpose -> BTR bf16 [B,D,S]
    transposeLN<<<dim3(32, 64, 8), dim3(32, 8), 0, stream>>>(P0, rowS, rowQ,
                                                             ln_g, ln_b, BTR);
    // forward FFT (packed-bf16 half-spectrum) + complexity counts
    fft_fwd<<<BD_ROWS, 256, 0, stream>>>(BTR, Xs, counts);
    calc_n<<<1, 64, 0, stream>>>(counts, Ndev);
    // masked inverse FFT -> P1 bf16 [B,D,S]
    fft_inv<<<BD_ROWS, 256, 0, stream>>>(Xs, Ndev, P1);
    // [B,D,S] -> [B,S,D] bf16 -> P0 flat (x_ifft_raw)
    transpose_bb<<<dim3(64, 32, 8), dim3(32, 8), 0, stream>>>(P1, P0, D_DIM, S_LEN);
    // proj_out = x_ifft_raw @ proj_w + b -> P1 bf16 + row LN-stats atomics
    gemm_8ph<<<dim3(4, 64), 512, 0, stream>>>(P0, WT + 6u * (1u << 20), proj_b,
                                              P1, rowS2, rowQ2);
    // x_ifft = LN(proj_out) -> d_out + cos/l1 row stats
    ln_loss<<<R_ROWS, 256, 0, stream>>>(P1, ln_g, ln_b, out, rowS2, rowQ2, rowA, rowL1);
    // fused ph stats: masked interleaved-B 8-phase GEMM (rows s < N[b] only)
    phstats_8ph<<<dim3(8, 32), 512, 0, stream>>>(P1, WTI, ph_b, vg, c0,
                                                 rowS2, rowQ2, Ndev, Sxx, Stt, Sxt);
    final_loss<<<1, 1024, 0, stream>>>(rowA, rowL1, Sxx, Stt, Sxt, Ndev, out);
}

// Round 13
// 512.656 us; speedup vs baseline: 1.0899x; 1.0899x over previous
//
#include <hip/hip_runtime.h>
#include <math.h>

#define S_LEN 2048
#define D_DIM 1024
#define B_BATCH 8
#define R_ROWS (B_BATCH * S_LEN)    // 16384
#define BD_ROWS (B_BATCH * D_DIM)   // 8192
#define PAD_ROWS 2050               // 1 zero row + 2048 + 1 zero row per batch

typedef unsigned short u16;
typedef unsigned int u32;
typedef __attribute__((ext_vector_type(8))) short bf16x8;
typedef __attribute__((ext_vector_type(4))) float f32x4;

__device__ __forceinline__ u16 f2bf(float f) {
    u32 x = __float_as_uint(f);
    u32 r = (x + 0x7fffu + ((x >> 16) & 1u)) >> 16;   // RNE
    return (u16)r;
}
__device__ __forceinline__ float bf2f(u16 u) {
    return __uint_as_float(((u32)u) << 16);
}
__device__ __forceinline__ float gelu_exact(float x) {
    return 0.5f * x * (1.0f + erff(x * 0.70710678118654752f));
}
// base-4 digit reverse of a 10-bit index
__device__ __forceinline__ int dr4(int v) {
    v = __brev((unsigned)v) >> 22;
    return ((v & 0x155) << 1) | ((v >> 1) & 0x155);
}
#define PIDX(i) ((i) + ((i) >> 5))   // LDS pad: +1 float per 32

#define GLDS(gsrc, ldst)                                                                   \
    __builtin_amdgcn_global_load_lds(                                                      \
        (const __attribute__((address_space(1))) u32*)(gsrc),                              \
        (__attribute__((address_space(3))) u32*)(ldst), 16, 0, 0)

#define WAIT_LGKM0 do { asm volatile("s_waitcnt lgkmcnt(0)" ::: "memory");                 \
                        __builtin_amdgcn_sched_barrier(0); } while (0)
#define WAIT_VM(n)   do { asm volatile("s_waitcnt vmcnt(" #n ")" ::: "memory");            \
                          __builtin_amdgcn_sched_barrier(0); } while (0)

// ----------------------------------------------------------- zero pad rows
__global__ __launch_bounds__(256) void zero_pads(u16* __restrict__ P0, u16* __restrict__ P1)
{
    const int bid = blockIdx.x;          // 0..31
    u16* P = (bid >= 16) ? P1 : P0;
    const int ridx = bid & 15;
    const int b = ridx >> 1;
    const size_t row = (size_t)b * PAD_ROWS + (size_t)(ridx & 1) * (PAD_ROWS - 1);
    ((uint2*)(P + row * D_DIM))[threadIdx.x] = make_uint2(0u, 0u);
}

// ------------------- merged weight prep: all transposes + WTI in one launch
// z 0-2: conv1 taps -> slots 0-2; z 3-5: conv2 taps -> slots 3-5; z 6: proj ->
// slot 6; z 7: ph interleave -> slots 7-8 (WTI[2n][k]=W[k][n], WTI[2n+1]=*g[k])
__global__ __launch_bounds__(256) void wprep(
    const float* __restrict__ c1, const float* __restrict__ c2,
    const float* __restrict__ pj, const float* __restrict__ ph,
    const float* __restrict__ g, u16* __restrict__ WT)
{
    __shared__ float t[32][33];
    const int z = blockIdx.z;
    const int n0 = blockIdx.x * 32, k0 = blockIdx.y * 32;
    const int tx = threadIdx.x, ty = threadIdx.y;
    const float* src;
    if (z < 3)      src = c1 + (size_t)z * D_DIM * D_DIM;
    else if (z < 6) src = c2 + (size_t)(z - 3) * D_DIM * D_DIM;
    else if (z == 6) src = pj;
    else            src = ph;
#pragma unroll
    for (int u = 0; u < 4; u++)
        t[ty + u * 8][tx] = src[(size_t)(k0 + ty + u * 8) * D_DIM + n0 + tx];
    __syncthreads();
    if (z < 7) {
        u16* op = WT + (size_t)z * D_DIM * D_DIM;
#pragma unroll
        for (int u = 0; u < 4; u++)
            op[(size_t)(n0 + ty + u * 8) * D_DIM + k0 + tx] = f2bf(t[tx][ty + u * 8]);
    } else {
        u16* WTI = WT + 7u * (1u << 20);
        const float gk = g[k0 + tx];
#pragma unroll
        for (int u = 0; u < 4; u++) {
            const int n = n0 + ty + u * 8;
            const float w = t[tx][ty + u * 8];
            WTI[((size_t)(2 * n) << 10) + k0 + tx] = f2bf(w);
            WTI[((size_t)(2 * n + 1) << 10) + k0 + tx] = f2bf(w * gk);
        }
    }
}

// -------- vg[n] = sum_k WTI[2n+1][k]; c0[n] = sum_k lnb[k]*WTI[2n][k] + phb[n]
__global__ __launch_bounds__(256) void gemv_ph(
    const u16* __restrict__ WTI, const float* __restrict__ lnb,
    const float* __restrict__ phb, float* __restrict__ vg, float* __restrict__ c0)
{
    const int wid = threadIdx.x >> 6, lane = threadIdx.x & 63;
    const int n = blockIdx.x * 4 + wid;   // grid 256
    const u16* r0 = WTI + ((size_t)(2 * n) << 10) + lane * 16;
    const u16* r1 = WTI + ((size_t)(2 * n + 1) << 10) + lane * 16;
    float sb = 0.f, sg = 0.f;
#pragma unroll
    for (int h = 0; h < 2; h++) {
        uint4 w0 = *(const uint4*)(r0 + h * 8);
        uint4 w1 = *(const uint4*)(r1 + h * 8);
        float a[8], b8[8];
        a[0] = bf2f((u16)(w0.x & 0xffff)); a[1] = bf2f((u16)(w0.x >> 16));
        a[2] = bf2f((u16)(w0.y & 0xffff)); a[3] = bf2f((u16)(w0.y >> 16));
        a[4] = bf2f((u16)(w0.z & 0xffff)); a[5] = bf2f((u16)(w0.z >> 16));
        a[6] = bf2f((u16)(w0.w & 0xffff)); a[7] = bf2f((u16)(w0.w >> 16));
        b8[0] = bf2f((u16)(w1.x & 0xffff)); b8[1] = bf2f((u16)(w1.x >> 16));
        b8[2] = bf2f((u16)(w1.y & 0xffff)); b8[3] = bf2f((u16)(w1.y >> 16));
        b8[4] = bf2f((u16)(w1.z & 0xffff)); b8[5] = bf2f((u16)(w1.z >> 16));
        b8[6] = bf2f((u16)(w1.w & 0xffff)); b8[7] = bf2f((u16)(w1.w >> 16));
        const int kb = lane * 16 + h * 8;
        float4 l0 = *(const float4*)(lnb + kb), l1 = *(const float4*)(lnb + kb + 4);
        sb += a[0]*l0.x + a[1]*l0.y + a[2]*l0.z + a[3]*l0.w
            + a[4]*l1.x + a[5]*l1.y + a[6]*l1.z + a[7]*l1.w;
        sg += b8[0] + b8[1] + b8[2] + b8[3] + b8[4] + b8[5] + b8[6] + b8[7];
    }
#pragma unroll
    for (int off = 32; off > 0; off >>= 1) {
        sg += __shfl_xor(sg, off);
        sb += __shfl_xor(sb, off);
    }
    if (lane == 0) { vg[n] = sg; c0[n] = sb + phb[n]; }
}

// ---------------------------------------------------------------- embedding
__global__ __launch_bounds__(256) void emb_kernel(
    const int* __restrict__ x, const float* __restrict__ tok,
    const float* __restrict__ pos, u16* __restrict__ P0)
{
    const int row = blockIdx.x;          // b*S + s
    const int tid = threadIdx.x;
    const int t = x[row];
    const int s = row & (S_LEN - 1);
    const int b = row >> 11;
    float4 a = ((const float4*)(tok + (size_t)t * D_DIM))[tid];
    float4 p = ((const float4*)(pos + (size_t)s * D_DIM))[tid];
    uint2 v;
    v.x = (u32)f2bf(a.x + p.x) | ((u32)f2bf(a.y + p.y) << 16);
    v.y = (u32)f2bf(a.z + p.z) | ((u32)f2bf(a.w + p.w) << 16);
    ((uint2*)(P0 + ((size_t)b * PAD_ROWS + 1 + s) * D_DIM))[tid] = v;
}

// ============ 256x256 BK=64 8-wave, 8-phase counted-vmcnt MFMA GEMM ==========
// Conflict-free swizzle (verified: SQ_LDS_BANK_CONFLICT = 0): logical k-chunk
// stored at q = c ^ ((row>>1)&3), applied on GLOBAL source; LDS dest linear.
// Handles conv taps (ntaps, padded A) and optional fused row sum/sumsq.
__global__ __launch_bounds__(512, 2) void gemm_8ph(
    const u16* __restrict__ A, const u16* __restrict__ WT,
    const float* __restrict__ bias, u16* __restrict__ outB,
    float* __restrict__ rowS, float* __restrict__ rowQ,
    int ntaps, int doGelu, int aPadded, int outBPadded)
{
    __shared__ u16 As[2][2][8192];    // [dbuf][ks-half][256 rows x 32 k]
    __shared__ u16 Bs[2][2][8192];    // [dbuf][ks-half][256 cols x 32 k]
    const int tid = threadIdx.x;
    const int wid = tid >> 6, lane = tid & 63;
    const int wm = wid >> 2, wn = wid & 3;
    const int l15 = lane & 15, l4 = lane >> 4;
    // grid (4,64): XCD-bijective swizzle, each XCD owns 8 contiguous M-panels
    const int flat = blockIdx.y * 4 + blockIdx.x;
    const int xcd = flat & 7;
    const int ii = flat >> 3;          // 0..31
    const int by = xcd * 8 + (ii >> 2);
    const int bx = ii & 3;
    const int row0 = by * 256;
    const int col0 = bx * 256;
    const int b = row0 >> 11;
    const int srow0 = row0 & (S_LEN - 1);
    const int nt = ntaps * 16;         // K-tiles of 64
    const int NI = nt >> 1;            // iterations (2 K-tiles each)

    const int stR = tid >> 2;                                   // row 0..127 (+128 on j=1)
    const int stKc = (((tid & 3) ^ ((tid >> 3) & 3)) << 3);     // logical k-chunk (elems)
    const int ldsOff = tid * 16;                                // linear LDS byte offset
    const int swz4 = ((l4 ^ ((l15 >> 1) & 3)) << 4);

#define STAGE_A(T_, s_) do {                                                               \
        const int tap_ = (T_) >> 4;                                                        \
        const int kb_ = ((T_) & 15) * 64 + (s_) * 32 + stKc;                               \
        const size_t ar_ = (aPadded ? (size_t)(b * PAD_ROWS + srow0 + tap_)                \
                                    : (size_t)row0);                                       \
        GLDS(A + ((ar_ + stR) << 10) + kb_,                                                \
             (char*)&As[(T_) & 1][s_][0] + ldsOff);                                        \
        GLDS(A + ((ar_ + stR + 128) << 10) + kb_,                                          \
             (char*)&As[(T_) & 1][s_][0] + ldsOff + 8192);                                 \
    } while (0)
#define STAGE_B(T_, s_) do {                                                               \
        const int tap_ = (T_) >> 4;                                                        \
        const int kb_ = ((T_) & 15) * 64 + (s_) * 32 + stKc;                               \
        const u16* wp_ = WT + ((size_t)tap_ << 20) + ((size_t)(col0 + stR) << 10) + kb_;   \
        GLDS(wp_, (char*)&Bs[(T_) & 1][s_][0] + ldsOff);                                   \
        GLDS(wp_ + (size_t)(128 << 10), (char*)&Bs[(T_) & 1][s_][0] + ldsOff + 8192);      \
    } while (0)
#define RD_A(dst_, buf_, s_, mih_) do {                                                    \
        const char* p_ = (const char*)&As[buf_][s_][0]                                     \
                         + (size_t)(wm * 128 + (mih_) * 64 + l15) * 64 + swz4;             \
        dst_[0] = *(const bf16x8*)(p_);                                                    \
        dst_[1] = *(const bf16x8*)(p_ + 1024);                                             \
        dst_[2] = *(const bf16x8*)(p_ + 2048);                                             \
        dst_[3] = *(const bf16x8*)(p_ + 3072);                                             \
    } while (0)
#define RD_B(dst_, buf_, s_) do {                                                          \
        const char* p_ = (const char*)&Bs[buf_][s_][0]                                     \
                         + (size_t)(wn * 64 + l15) * 64 + swz4;                            \
        dst_[0] = *(const bf16x8*)(p_);                                                    \
        dst_[1] = *(const bf16x8*)(p_ + 1024);                                             \
        dst_[2] = *(const bf16x8*)(p_ + 2048);                                             \
        dst_[3] = *(const bf16x8*)(p_ + 3072);                                             \
    } while (0)
#define MF(mih_, av_, bv_) do {                                                            \
        __builtin_amdgcn_s_setprio(1);                                                     \
        _Pragma("unroll")                                                                  \
        for (int mi_ = 0; mi_ < 4; mi_++)                                                  \
            _Pragma("unroll")                                                              \
            for (int ni_ = 0; ni_ < 4; ni_++)                                              \
                acc[(mih_) * 4 + mi_][ni_] = __builtin_amdgcn_mfma_f32_16x16x32_bf16(      \
                    av_[mi_], bv_[ni_], acc[(mih_) * 4 + mi_][ni_], 0, 0, 0);              \
        __builtin_amdgcn_s_setprio(0);                                                     \
    } while (0)
#define BAR __builtin_amdgcn_s_barrier()

    f32x4 acc[8][4];
#pragma unroll
    for (int m = 0; m < 8; m++)
#pragma unroll
        for (int n = 0; n < 4; n++) acc[m][n] = (f32x4){0.f, 0.f, 0.f, 0.f};

    // prologue: tile0 (both halves) + tile1.ks0 staged; gate leaves tile1.ks0 in flight
    STAGE_A(0, 0); STAGE_B(0, 0);
    STAGE_A(0, 1); STAGE_B(0, 1);
    STAGE_A(1, 0); STAGE_B(1, 0);
    WAIT_VM(4);
    BAR;

    for (int i = 0; i < NI; ++i) {
        const int o = 2 * i + 1;
        const int e2 = 2 * i + 2, o2 = 2 * i + 3;
        const bool last = (i == NI - 1);
        bf16x8 a[4], bv[4];
        // ---- ph0: tile e, ks0, mi 0-3
        RD_A(a, 0, 0, 0); RD_B(bv, 0, 0);
        STAGE_A(o, 1);
        BAR; WAIT_LGKM0;
        MF(0, a, bv);
        BAR;
        // ---- ph1: tile e, ks0, mi 4-7 (reuse B frags)
        RD_A(a, 0, 0, 1);
        STAGE_B(o, 1);
        BAR; WAIT_LGKM0;
        MF(1, a, bv);
        BAR;
        // ---- ph2: tile e, ks1, mi 0-3
        RD_A(a, 0, 1, 0); RD_B(bv, 0, 1);
        if (!last) STAGE_A(e2, 0);
        BAR; WAIT_LGKM0;
        MF(0, a, bv);
        BAR;
        // ---- ph3: tile e, ks1, mi 4-7  [gate: tile o fully landed]
        RD_A(a, 0, 1, 1);
        if (!last) STAGE_B(e2, 0);
        BAR; WAIT_LGKM0;
        MF(1, a, bv);
        if (last) { WAIT_VM(0); } else { WAIT_VM(4); }
        BAR;
        // ---- ph4: tile o, ks0, mi 0-3
        RD_A(a, 1, 0, 0); RD_B(bv, 1, 0);
        if (!last) STAGE_A(e2, 1);
        BAR; WAIT_LGKM0;
        MF(0, a, bv);
        BAR;
        // ---- ph5: tile o, ks0, mi 4-7
        RD_A(a, 1, 0, 1);
        if (!last) STAGE_B(e2, 1);
        BAR; WAIT_LGKM0;
        MF(1, a, bv);
        BAR;
        // ---- ph6: tile o, ks1, mi 0-3
        RD_A(a, 1, 1, 0); RD_B(bv, 1, 1);
        if (!last) STAGE_A(o2, 0);
        BAR; WAIT_LGKM0;
        MF(0, a, bv);
        BAR;
        // ---- ph7: tile o, ks1, mi 4-7  [gate: tile e2 fully landed]
        RD_A(a, 1, 1, 1);
        if (!last) STAGE_B(o2, 0);
        BAR; WAIT_LGKM0;
        MF(1, a, bv);
        if (!last) { WAIT_VM(4); }
        BAR;
    }
#undef STAGE_A

    float bb[4];
#pragma unroll
    for (int ni = 0; ni < 4; ni++) bb[ni] = bias[col0 + wn * 64 + ni * 16 + l15];

#pragma unroll
    for (int mi = 0; mi < 8; mi++) {
#pragma unroll
        for (int reg = 0; reg < 4; reg++) {
            const int row = row0 + wm * 128 + mi * 16 + l4 * 4 + reg;
            float s_ = 0.f, q_ = 0.f;
#pragma unroll
            for (int ni = 0; ni < 4; ni++) {
                const int col = col0 + wn * 64 + ni * 16 + l15;
                float v = acc[mi][ni][reg] + bb[ni];
                if (doGelu) v = gelu_exact(v);
                const size_t orow = outBPadded
                    ? ((size_t)(row >> 11) * PAD_ROWS + 1 + (size_t)(row & (S_LEN - 1)))
                    : (size_t)row;
                outB[orow * D_DIM + col] = f2bf(v);
                if (rowS) { s_ += v; q_ = fmaf(v, v, q_); }
            }
            if (rowS) {
#pragma unroll
                for (int off = 1; off < 16; off <<= 1) {
                    s_ += __shfl_xor(s_, off);
                    q_ += __shfl_xor(q_, off);
                }
                if (l15 == 0) {
                    atomicAdd(&rowS[row], s_);
                    atomicAdd(&rowQ[row], q_);
                }
            }
        }
    }
}

// ====== ph-stats via interleaved-B 8-phase GEMM, MASKED rows only ======
// sem contributes only for s < N[b] <= 1024. Grid covers rows
// [b*2048, b*2048+1024); blocks with local row-start >= N[b] exit immediately.
__global__ __launch_bounds__(512, 2) void phstats_8ph(
    const u16* __restrict__ A, const u16* __restrict__ WTI,
    const float* __restrict__ phb, const float* __restrict__ vg,
    const float* __restrict__ c0,
    const float* __restrict__ rowS2, const float* __restrict__ rowQ2,
    const int* __restrict__ Ndev,
    float* __restrict__ Sxx, float* __restrict__ Stt, float* __restrict__ Sxt)
{
    __shared__ u16 As[2][2][8192];
    __shared__ u16 Bs[2][2][8192];
    const int tid = threadIdx.x;
    const int wid = tid >> 6, lane = tid & 63;
    const int wm = wid >> 2, wn = wid & 3;
    const int l15 = lane & 15, l4 = lane >> 4;
    // grid (8,32): 256 blocks; XCD-bijective
    const int flat = blockIdx.y * 8 + blockIdx.x;
    const int xcd = flat & 7;
    const int ii = flat >> 3;          // 0..31
    const int by = xcd * 4 + (ii >> 3);   // 0..31 row-blocks
    const int bx = ii & 7;                // 0..7 col-blocks
    const int batch = by >> 2;
    const int rb = by & 3;
    if (rb * 256 >= Ndev[batch]) return;
    const int row0 = batch * S_LEN + rb * 256;
    const int col0 = bx * 256;         // of 2048
    const int NI = 8;                  // K=1024, 16 K-tiles, 2/iter

    const int stR = tid >> 2;
    const int stKc = (((tid & 3) ^ ((tid >> 3) & 3)) << 3);
    const int ldsOff = tid * 16;
    const int swz4 = ((l4 ^ ((l15 >> 1) & 3)) << 4);

#define STAGE_A(T_, s_) do {                                                               \
        const int kb_ = ((T_) & 15) * 64 + (s_) * 32 + stKc;                               \
        GLDS(A + (((size_t)row0 + stR) << 10) + kb_,                                       \
             (char*)&As[(T_) & 1][s_][0] + ldsOff);                                        \
        GLDS(A + (((size_t)row0 + stR + 128) << 10) + kb_,                                 \
             (char*)&As[(T_) & 1][s_][0] + ldsOff + 8192);                                 \
    } while (0)
#define STAGE_BI(T_, s_) do {                                                              \
        const int kb_ = ((T_) & 15) * 64 + (s_) * 32 + stKc;                               \
        const u16* wp_ = WTI + ((size_t)(col0 + stR) << 10) + kb_;                         \
        GLDS(wp_, (char*)&Bs[(T_) & 1][s_][0] + ldsOff);                                   \
        GLDS(wp_ + (size_t)(128 << 10), (char*)&Bs[(T_) & 1][s_][0] + ldsOff + 8192);      \
    } while (0)

    f32x4 acc[8][4];
#pragma unroll
    for (int m = 0; m < 8; m++)
#pragma unroll
        for (int n = 0; n < 4; n++) acc[m][n] = (f32x4){0.f, 0.f, 0.f, 0.f};

    STAGE_A(0, 0); STAGE_BI(0, 0);
    STAGE_A(0, 1); STAGE_BI(0, 1);
    STAGE_A(1, 0); STAGE_BI(1, 0);
    WAIT_VM(4);
    BAR;

    for (int i = 0; i < NI; ++i) {
        const int o = 2 * i + 1;
        const int e2 = 2 * i + 2, o2 = 2 * i + 3;
        const bool last = (i == NI - 1);
        bf16x8 a[4], bv[4];
        RD_A(a, 0, 0, 0); RD_B(bv, 0, 0);
        STAGE_A(o, 1);
        BAR; WAIT_LGKM0;
        MF(0, a, bv);
        BAR;
        RD_A(a, 0, 0, 1);
        STAGE_BI(o, 1);
        BAR; WAIT_LGKM0;
        MF(1, a, bv);
        BAR;
        RD_A(a, 0, 1, 0); RD_B(bv, 0, 1);
        if (!last) STAGE_A(e2, 0);
        BAR; WAIT_LGKM0;
        MF(0, a, bv);
        BAR;
        RD_A(a, 0, 1, 1);
        if (!last) STAGE_BI(e2, 0);
        BAR; WAIT_LGKM0;
        MF(1, a, bv);
        if (last) { WAIT_VM(0); } else { WAIT_VM(4); }
        BAR;
        RD_A(a, 1, 0, 0); RD_B(bv, 1, 0);
        if (!last) STAGE_A(e2, 1);
        BAR; WAIT_LGKM0;
        MF(0, a, bv);
        BAR;
        RD_A(a, 1, 0, 1);
        if (!last) STAGE_BI(e2, 1);
        BAR; WAIT_LGKM0;
        MF(1, a, bv);
        BAR;
        RD_A(a, 1, 1, 0); RD_B(bv, 1, 1);
        if (!last) STAGE_A(o2, 0);
        BAR; WAIT_LGKM0;
        MF(0, a, bv);
        BAR;
        RD_A(a, 1, 1, 1);
        if (!last) STAGE_BI(o2, 0);
        BAR; WAIT_LGKM0;
        MF(1, a, bv);
        if (!last) { WAIT_VM(4); }
        BAR;
    }
#undef STAGE_A
#undef STAGE_BI
#undef RD_A
#undef RD_B
#undef MF
#undef BAR

    // epilogue: pt/px pairing and row stats
    float phv[4], vgv[4], c0v[4];
#pragma unroll
    for (int ni = 0; ni < 4; ni++) {
        const int col = col0 + wn * 64 + ni * 16 + l15;
        const int j = col >> 1;
        phv[ni] = phb[j]; vgv[ni] = vg[j]; c0v[ni] = c0[j];
    }
    const bool odd = (l15 & 1) != 0;
#pragma unroll
    for (int mi = 0; mi < 8; mi++) {
#pragma unroll
        for (int reg = 0; reg < 4; reg++) {
            const int row = row0 + wm * 128 + mi * 16 + l4 * 4 + reg;
            const float mS = rowS2[row] * (1.0f / D_DIM);
            const float var = rowQ2[row] * (1.0f / D_DIM) - mS * mS;
            const float rsv = rsqrtf(var + 1e-5f);
            const float mrs = mS * rsv;
            float sxx = 0.f, stt = 0.f, sxt = 0.f;
#pragma unroll
            for (int ni = 0; ni < 4; ni++) {
                const float raw = acc[mi][ni][reg];
                const float val = odd ? (rsv * raw - mrs * vgv[ni] + c0v[ni])
                                      : (raw + phv[ni]);
                const float par = __shfl_xor(val, 1);
                const float pt = odd ? par : val;
                const float px = odd ? val : par;
                stt = fmaf(pt, pt, stt);
                sxx = fmaf(px, px, sxx);
                sxt = fmaf(pt, px, sxt);
            }
#pragma unroll
            for (int off = 1; off < 16; off <<= 1) {
                sxx += __shfl_xor(sxx, off);
                stt += __shfl_xor(stt, off);
                sxt += __shfl_xor(sxt, off);
            }
            if (l15 == 0) {
                atomicAdd(&Sxx[row], 0.5f * sxx);
                atomicAdd(&Stt[row], 0.5f * stt);
                atomicAdd(&Sxt[row], 0.5f * sxt);
            }
        }
    }
}

// ------- fused LN + transpose: bf16 [B,S,D] -> bf16 [B,D,S]; stats from rowS/rowQ
__global__ __launch_bounds__(256) void transposeLN(
    const u16* __restrict__ in, const float* __restrict__ rowS,
    const float* __restrict__ rowQ,
    const float* __restrict__ g, const float* __restrict__ beta,
    u16* __restrict__ out)
{
    __shared__ float t[32][33];
    const int b = blockIdx.z;
    const int n0 = blockIdx.x * 32, m0 = blockIdx.y * 32;   // n=d, m=s
    const int tx = threadIdx.x, ty = threadIdx.y;
    const u16* ip = in + (size_t)b * S_LEN * D_DIM;
    u16* op = out + (size_t)b * S_LEN * D_DIM;
#pragma unroll
    for (int u = 0; u < 4; u++)
        t[ty + u * 8][tx] = bf2f(ip[(size_t)(m0 + ty + u * 8) * D_DIM + n0 + tx]);
    __syncthreads();
    const int row = b * S_LEN + m0 + tx;
    const float mS = rowS[row] * (1.0f / D_DIM);
    const float var = rowQ[row] * (1.0f / D_DIM) - mS * mS;
    const float rs = rsqrtf(var + 1e-5f);
#pragma unroll
    for (int u = 0; u < 4; u++) {
        const int d = n0 + ty + u * 8;
        const float val = (t[tx][ty + u * 8] - mS) * rs * g[d] + beta[d];
        op[(size_t)d * S_LEN + m0 + tx] = f2bf(val);
    }
}

// --------------------- forward real-FFT: 2048-pt via 1024-pt radix-4 packing
// input bf16 [B,D,S]; spectrum stored as packed bf16 pairs.
__global__ __launch_bounds__(256) void fft_fwd(
    const u16* __restrict__ in, u32* __restrict__ X, int* __restrict__ counts)
{
    __shared__ float re[1056], im[1056], twr[1024], twi[1024];
    __shared__ float redf[4];
    __shared__ int redi[4];
    const int tid = threadIdx.x;
    const int row = blockIdx.x;          // b*D + d
    const u32* src = (const u32*)(in + (size_t)row * S_LEN);
#pragma unroll
    for (int u = 0; u < 4; u++) {
        int e = tid + u * 256;
        float ang = -3.14159265358979f * (float)e * (1.0f / 512.0f);
        float sn, cs; __sincosf(ang, &sn, &cs);
        twr[e] = cs; twi[e] = sn;
    }
#pragma unroll
    for (int u = 0; u < 4; u++) {
        int t = tid + u * 256;
        u32 w = src[t];                  // z[t] = x[2t] + i x[2t+1]
        int p = PIDX(dr4(t));
        re[p] = bf2f((u16)(w & 0xffff)); im[p] = bf2f((u16)(w >> 16));
    }
    __syncthreads();
#pragma unroll
    for (int s = 1; s <= 5; ++s) {
        const int mq = 1 << (2 * (s - 1));
        const int fsh = 2 * (5 - s);
        const int j = tid & (mq - 1);
        const int g = tid >> (2 * (s - 1));
        const int i0 = (g << (2 * s)) + j;
        const int e1 = j << fsh;
        const int p0 = PIDX(i0), p1 = PIDX(i0 + mq), p2 = PIDX(i0 + 2 * mq), p3 = PIDX(i0 + 3 * mq);
        float a0r = re[p0], a0i = im[p0];
        float a1r = re[p1], a1i = im[p1];
        float a2r = re[p2], a2i = im[p2];
        float a3r = re[p3], a3i = im[p3];
        float w1r = twr[e1], w1i = twi[e1];
        float w2r = twr[2 * e1], w2i = twi[2 * e1];
        float w3r = twr[3 * e1], w3i = twi[3 * e1];
        float b1r = a1r * w1r - a1i * w1i, b1i = a1r * w1i + a1i * w1r;
        float b2r = a2r * w2r - a2i * w2i, b2i = a2r * w2i + a2i * w2r;
        float b3r = a3r * w3r - a3i * w3i, b3i = a3r * w3i + a3i * w3r;
        float t0r = a0r + b2r, t0i = a0i + b2i;
        float t1r = a0r - b2r, t1i = a0i - b2i;
        float t2r = b1r + b3r, t2i = b1i + b3i;
        float t3r = b1r - b3r, t3i = b1i - b3i;
        re[p0] = t0r + t2r; im[p0] = t0i + t2i;
        re[p2] = t0r - t2r; im[p2] = t0i - t2i;
        re[p1] = t1r + t3i; im[p1] = t1i - t3r;   // t1 - i*t3
        re[p3] = t1r - t3i; im[p3] = t1i + t3r;   // t1 + i*t3
        __syncthreads();
    }
    u32* dst = X + (size_t)row * 1024;
    float mag[4];
    float xtra = 0.0f;
    float lmax = 0.0f;
#pragma unroll
    for (int u = 0; u < 4; u++) {
        int k = tid + u * 256;
        int mk = (1024 - k) & 1023;
        float rk = re[PIDX(k)], ik = im[PIDX(k)];
        float rm = re[PIDX(mk)], imm = im[PIDX(mk)];
        float er = 0.5f * (rk + rm);
        float ei = 0.5f * (ik - imm);
        float orr = 0.5f * (ik + imm);
        float oii = -0.5f * (rk - rm);
        float ang = -3.14159265358979f * (float)k * (1.0f / 1024.0f);
        float sn, cs; __sincosf(ang, &sn, &cs);
        float xr = er + orr * cs - oii * sn;
        float xi = ei + orr * sn + oii * cs;
        dst[k] = (u32)f2bf(xr) | ((u32)f2bf(xi) << 16);
        float m2 = xr * xr + xi * xi;
        mag[u] = m2;
        lmax = fmaxf(lmax, m2);
        if (k == 0) {
            float x1024 = re[PIDX(0)] - im[PIDX(0)];
            xtra = x1024 * x1024;
            lmax = fmaxf(lmax, xtra);
        }
    }
#pragma unroll
    for (int off = 32; off > 0; off >>= 1) lmax = fmaxf(lmax, __shfl_xor(lmax, off));
    if ((tid & 63) == 0) redf[tid >> 6] = lmax;
    __syncthreads();
    const float bmax = fmaxf(fmaxf(redf[0], redf[1]), fmaxf(redf[2], redf[3]));
    const float thr = 0.01f * bmax;
    int lc = 0;
#pragma unroll
    for (int u = 0; u < 4; u++) {
        int k = tid + u * 256;
        lc += (mag[u] > thr) ? ((k == 0) ? 1 : 2) : 0;
    }
    if (tid == 0) lc += (xtra > thr) ? 1 : 0;
#pragma unroll
    for (int off = 32; off > 0; off >>= 1) lc += __shfl_xor(lc, off);
    if ((tid & 63) == 0) redi[tid >> 6] = lc;
    __syncthreads();
    if (tid == 0)
        atomicAdd(&counts[(row >> 10) * 64 + (row & 63)],
                  redi[0] + redi[1] + redi[2] + redi[3]);
}

// ------------------------------------------------------------- N from counts
__global__ void calc_n(const int* __restrict__ counts, int* __restrict__ Ndev)
{
    const int t = threadIdx.x;           // 64 threads
    for (int b = 0; b < B_BATCH; b++) {
        int c = counts[b * 64 + t];
#pragma unroll
        for (int off = 32; off > 0; off >>= 1) c += __shfl_xor(c, off);
        if (t == 0) {
            float cf = (float)c * (1.0f / 2097152.0f);
            float cr = 0.5f * (1.0f - cf);
            cr = fminf(fmaxf(cr, 0.1f), 1.0f);
            int n = (int)(cr * 2048.0f);
            n = n < 1 ? 1 : (n > S_LEN ? S_LEN : n);
            Ndev[b] = n;
        }
    }
}

// --------------------- masked inverse 2048-ifft (real part) -> bf16 [B,D,S]
__global__ __launch_bounds__(256) void fft_inv(
    const u32* __restrict__ X, const int* __restrict__ Ndev,
    u16* __restrict__ outb)
{
    __shared__ float re[1056], im[1056], twr[1024], twi[1024];
    const int tid = threadIdx.x;
    const int row = blockIdx.x;          // b*D + d
    const int Nb = Ndev[row >> 10];
    const u32* src = X + (size_t)row * 1024;
#pragma unroll
    for (int u = 0; u < 4; u++) {
        int e = tid + u * 256;
        float ang = 3.14159265358979f * (float)e * (1.0f / 512.0f);
        float sn, cs; __sincosf(ang, &sn, &cs);
        twr[e] = cs; twi[e] = sn;
    }
#pragma unroll
    for (int u = 0; u < 4; u++) {
        int k = tid + u * 256;
        float Ar = 0.f, Ai = 0.f, Br = 0.f, Bi = 0.f;
        if (k == 0) {
            u32 w = src[0];
            Ar = bf2f((u16)(w & 0xffff)); Ai = bf2f((u16)(w >> 16));
        } else {
            if (k < Nb) {
                u32 w = src[k];
                Ar = 0.5f * bf2f((u16)(w & 0xffff));
                Ai = 0.5f * bf2f((u16)(w >> 16));
            }
            int km = 1024 - k;
            if (km < Nb) {
                u32 w = src[km];
                Br = 0.5f * bf2f((u16)(w & 0xffff));
                Bi = -0.5f * bf2f((u16)(w >> 16));
            }
        }
        float ang = 3.14159265358979f * (float)k * (1.0f / 1024.0f);
        float sn, cs; __sincosf(ang, &sn, &cs);
        float drr = Ar - Br, dri = Ai - Bi;
        float Dr = drr * cs - dri * sn;
        float Di = drr * sn + dri * cs;
        float Cr = (Ar + Br) - Di;
        float Ci = (Ai + Bi) + Dr;
        int p = PIDX(dr4(k));
        re[p] = Cr; im[p] = Ci;
    }
    __syncthreads();
#pragma unroll
    for (int s = 1; s <= 4; ++s) {
        const int mq = 1 << (2 * (s - 1));
        const int fsh = 2 * (5 - s);
        const int j = tid & (mq - 1);
        const int g = tid >> (2 * (s - 1));
        const int i0 = (g << (2 * s)) + j;
        const int e1 = j << fsh;
        const int p0 = PIDX(i0), p1 = PIDX(i0 + mq), p2 = PIDX(i0 + 2 * mq), p3 = PIDX(i0 + 3 * mq);
        float a0r = re[p0], a0i = im[p0];
        float a1r = re[p1], a1i = im[p1];
        float a2r = re[p2], a2i = im[p2];
        float a3r = re[p3], a3i = im[p3];
        float w1r = twr[e1], w1i = twi[e1];
        float w2r = twr[2 * e1], w2i = twi[2 * e1];
        float w3r = twr[3 * e1], w3i = twi[3 * e1];
        float b1r = a1r * w1r - a1i * w1i, b1i = a1r * w1i + a1i * w1r;
        float b2r = a2r * w2r - a2i * w2i, b2i = a2r * w2i + a2i * w2r;
        float b3r = a3r * w3r - a3i * w3i, b3i = a3r * w3i + a3i * w3r;
        float t0r = a0r + b2r, t0i = a0i + b2i;
        float t1r = a0r - b2r, t1i = a0i - b2i;
        float t2r = b1r + b3r, t2i = b1i + b3i;
        float t3r = b1r - b3r, t3i = b1i - b3i;
        re[p0] = t0r + t2r; im[p0] = t0i + t2i;
        re[p2] = t0r - t2r; im[p2] = t0i - t2i;
        re[p1] = t1r - t3i; im[p1] = t1i + t3r;   // t1 + i*t3
        re[p3] = t1r + t3i; im[p3] = t1i - t3r;   // t1 - i*t3
        __syncthreads();
    }
    // stage 5: registers -> global (packed bf16)
    {
        const int j = tid;               // mq = 256
        const int e1 = j;
        const int p0 = PIDX(j), p1 = PIDX(j + 256), p2 = PIDX(j + 512), p3 = PIDX(j + 768);
        float a0r = re[p0], a0i = im[p0];
        float a1r = re[p1], a1i = im[p1];
        float a2r = re[p2], a2i = im[p2];
        float a3r = re[p3], a3i = im[p3];
        float w1r = twr[e1], w1i = twi[e1];
        float w2r = twr[2 * e1], w2i = twi[2 * e1];
        float w3r = twr[3 * e1], w3i = twi[3 * e1];
        float b1r = a1r * w1r - a1i * w1i, b1i = a1r * w1i + a1i * w1r;
        float b2r = a2r * w2r - a2i * w2i, b2i = a2r * w2i + a2i * w2r;
        float b3r = a3r * w3r - a3i * w3i, b3i = a3r * w3i + a3i * w3r;
        float t0r = a0r + b2r, t0i = a0i + b2i;
        float t1r = a0r - b2r, t1i = a0i - b2i;
        float t2r = b1r + b3r, t2i = b1i + b3i;
        float t3r = b1r - b3r, t3i = b1i - b3i;
        const float sc = 1.0f / 2048.0f;
        u32* dst = (u32*)(outb + (size_t)row * S_LEN);
        dst[j]       = (u32)f2bf((t0r + t2r) * sc) | ((u32)f2bf((t0i + t2i) * sc) << 16);
        dst[j + 256] = (u32)f2bf((t1r - t3i) * sc) | ((u32)f2bf((t1i + t3r) * sc) << 16);
        dst[j + 512] = (u32)f2bf((t0r - t2r) * sc) | ((u32)f2bf((t0i - t2i) * sc) << 16);
        dst[j + 768] = (u32)f2bf((t1r + t3i) * sc) | ((u32)f2bf((t1i - t3r) * sc) << 16);
    }
}

// ---------------------- bf16 transpose [B][M][N] -> [B][N][M]
__global__ __launch_bounds__(256) void transpose_bb(
    const u16* __restrict__ in, u16* __restrict__ out, int M, int N)
{
    __shared__ u16 t[32][33];
    const int b = blockIdx.z;
    const int n0 = blockIdx.x * 32, m0 = blockIdx.y * 32;
    const int tx = threadIdx.x, ty = threadIdx.y;
    const u16* ip = in + (size_t)b * M * N;
    u16* op = out + (size_t)b * M * N;
#pragma unroll
    for (int u = 0; u < 4; u++)
        t[ty + u * 8][tx] = ip[(size_t)(m0 + ty + u * 8) * N + n0 + tx];
    __syncthreads();
#pragma unroll
    for (int u = 0; u < 4; u++)
        op[(size_t)(n0 + ty + u * 8) * M + m0 + tx] = t[tx][ty + u * 8];
}

// -------- LN(proj_out bf16) + cos-sim/smooth-L1 row stats; stats precomputed
__global__ __launch_bounds__(256) void ln_loss(
    const u16* __restrict__ in, const float* __restrict__ g,
    const float* __restrict__ beta, float* __restrict__ outF,
    const float* __restrict__ rowS2, const float* __restrict__ rowQ2,
    float* __restrict__ rowA, float* __restrict__ rowL1)
{
    const int row = blockIdx.x;
    const int tid = threadIdx.x;
    uint2 raw = ((const uint2*)(in + (size_t)row * D_DIM))[tid];
    float v0 = bf2f((u16)(raw.x & 0xffff)), v1 = bf2f((u16)(raw.x >> 16));
    float v2 = bf2f((u16)(raw.y & 0xffff)), v3 = bf2f((u16)(raw.y >> 16));
    const float m = rowS2[row] * (1.0f / D_DIM);
    const float var = rowQ2[row] * (1.0f / D_DIM) - m * m;
    const float rs = rsqrtf(var + 1e-5f);
    float4 gg = ((const float4*)g)[tid];
    float4 bb = ((const float4*)beta)[tid];
    float4 o;
    o.x = (v0 - m) * rs * gg.x + bb.x;
    o.y = (v1 - m) * rs * gg.y + bb.y;
    o.z = (v2 - m) * rs * gg.z + bb.z;
    o.w = (v3 - m) * rs * gg.w + bb.w;
    ((float4*)(outF + (size_t)row * D_DIM))[tid] = o;

    float xx = o.x * o.x + o.y * o.y + o.z * o.z + o.w * o.w;
    float rr = v0 * v0 + v1 * v1 + v2 * v2 + v3 * v3;
    float xr = o.x * v0 + o.y * v1 + o.z * v2 + o.w * v3;
    float l1 = 0.f;
    {
        float d, ad;
        d = o.x - v0; ad = fabsf(d); l1 += (ad < 1.0f) ? 0.5f * d * d : ad - 0.5f;
        d = o.y - v1; ad = fabsf(d); l1 += (ad < 1.0f) ? 0.5f * d * d : ad - 0.5f;
        d = o.z - v2; ad = fabsf(d); l1 += (ad < 1.0f) ? 0.5f * d * d : ad - 0.5f;
        d = o.w - v3; ad = fabsf(d); l1 += (ad < 1.0f) ? 0.5f * d * d : ad - 0.5f;
    }
#pragma unroll
    for (int off = 32; off > 0; off >>= 1) {
        xx += __shfl_xor(xx, off); rr += __shfl_xor(rr, off);
        xr += __shfl_xor(xr, off); l1 += __shfl_xor(l1, off);
    }
    __shared__ float red2[4][4];
    if ((tid & 63) == 0) {
        int w = tid >> 6;
        red2[w][0] = xx; red2[w][1] = rr; red2[w][2] = xr; red2[w][3] = l1;
    }
    __syncthreads();
    if (tid == 0) {
        xx = red2[0][0] + red2[1][0] + red2[2][0] + red2[3][0];
        rr = red2[0][1] + red2[1][1] + red2[2][1] + red2[3][1];
        xr = red2[0][2] + red2[1][2] + red2[2][2] + red2[3][2];
        l1 = red2[0][3] + red2[1][3] + red2[2][3] + red2[3][3];
        float nx = fmaxf(sqrtf(xx), 1e-12f);
        float nr = fmaxf(sqrtf(rr), 1e-12f);
        float cs = xr / (nx * nr);
        cs = fminf(fmaxf(cs, -1.0f + 1e-8f), 1.0f - 1e-8f);
        rowA[row] = 1.0f - cs;
        rowL1[row] = l1;
    }
}

// ------------------------------------------------------------- final loss
__global__ __launch_bounds__(1024) void final_loss(
    const float* __restrict__ rowA, const float* __restrict__ rowL1,
    const float* __restrict__ Sxx, const float* __restrict__ Stt,
    const float* __restrict__ Sxt,
    const int* __restrict__ Ndev, float* __restrict__ out)
{
    const int tid = threadIdx.x;
    float sa = 0.f, sb = 0.f;
#pragma unroll
    for (int i = 0; i < 16; i++) {
        int r = tid + i * 1024;
        sa += rowA[r];
        int b = r >> 11, s = r & (S_LEN - 1);
        if (s < Ndev[b]) {
            float sx = Sxx[r], st = Stt[r], sxtv = Sxt[r];
            float nxx = fmaxf(sqrtf(sx), 1e-12f);
            float ntt = fmaxf(sqrtf(st), 1e-12f);
            float sem = (sx / (nxx * nxx) + st / (ntt * ntt)
                         - 2.0f * sxtv / (nxx * ntt)) * (1.0f / D_DIM);
            sb += 0.2f * (rowL1[r] * (1.0f / D_DIM)) + 0.2f * sem;
        }
    }
#pragma unroll
    for (int off = 32; off > 0; off >>= 1) {
        sa += __shfl_xor(sa, off);
        sb += __shfl_xor(sb, off);
    }
    __shared__ float ra[16], rb[16];
    if ((tid & 63) == 0) { ra[tid >> 6] = sa; rb[tid >> 6] = sb; }
    __syncthreads();
    if (tid == 0) {
        float A = 0.f, Bs = 0.f;
#pragma unroll
        for (int i = 0; i < 16; i++) { A += ra[i]; Bs += rb[i]; }
        int K = 0;
        for (int b = 0; b < B_BATCH; b++) K += Ndev[b];
        float Kf = (float)K;
        float M = A * (1.0f / 16384.0f);
        out[(size_t)R_ROWS * D_DIM] = (0.6f * M * Kf + Bs) / (Kf + 1e-8f);
    }
}

// ---------------------------------------------------------------------------
extern "C" void kernel_launch(void* const* d_in, const int* in_sizes, int n_in,
                              void* d_out, int out_size, void* d_ws, size_t ws_size,
                              hipStream_t stream)
{
    (void)in_sizes; (void)n_in; (void)out_size; (void)ws_size;
    const int*   x       = (const int*)  d_in[0];
    const float* tok     = (const float*)d_in[1];
    const float* pos     = (const float*)d_in[2];
    const float* conv1_w = (const float*)d_in[3];
    const float* conv1_b = (const float*)d_in[4];
    const float* conv2_w = (const float*)d_in[5];
    const float* conv2_b = (const float*)d_in[6];
    const float* proj_w  = (const float*)d_in[7];
    const float* proj_b  = (const float*)d_in[8];
    const float* ph_w    = (const float*)d_in[9];
    const float* ph_b    = (const float*)d_in[10];
    const float* ln_g    = (const float*)d_in[11];
    const float* ln_b    = (const float*)d_in[12];
    float* out = (float*)d_out;

    char* ws = (char*)d_ws;
    int*    counts = (int*)(ws);                         // 512 ints
    int*    Ndev   = (int*)(ws + 2048);
    float*  Sxx    = (float*)(ws + 266240);
    float*  Stt    = (float*)(ws + 331776);
    float*  Sxt    = (float*)(ws + 397312);
    float*  rowA   = (float*)(ws + 462848);
    float*  rowL1  = (float*)(ws + 528384);
    float*  vg     = (float*)(ws + 593920);
    float*  c0     = (float*)(ws + 598016);
    float*  rowS   = (float*)(ws + 602112);              // conv2 row sums
    float*  rowQ   = (float*)(ws + 667648);
    float*  rowS2  = (float*)(ws + 733184);              // proj row sums
    float*  rowQ2  = (float*)(ws + 798720);              // ends 864256 < 1MB
    const size_t MB = 1ull << 20;
    u16*   WT   = (u16*)(ws + 1 * MB);      // 9 slots x 2MB (7-8 = WTI)
    u16*   WTI  = WT + 7u * (1u << 20);
    u16*   P0   = (u16*)(ws + 19 * MB);     // 32.03 MB padded bf16 activations
    u16*   P1   = (u16*)(ws + 52 * MB);     // 32.03 MB
    u32*   Xs   = (u32*)(ws + 85 * MB);     // 32 MiB packed-bf16 spectrum
    u16*   BTR  = (u16*)(ws + 118 * MB);    // 32 MiB LN'd bf16 [B,D,S]

    hipMemsetAsync(ws, 0, MB, stream);
    zero_pads<<<32, 256, 0, stream>>>(P0, P1);
    wprep<<<dim3(32, 32, 8), dim3(32, 8), 0, stream>>>(conv1_w, conv2_w, proj_w,
                                                       ph_w, ln_g, WT);
    gemv_ph<<<256, 256, 0, stream>>>(WTI, ln_b, ph_b, vg, c0);
    // h0 (padded bf16)
    emb_kernel<<<R_ROWS, 256, 0, stream>>>(x, tok, pos, P0);
    // h1 = gelu(conv1(h0)) -> P1 padded
    gemm_8ph<<<dim3(4, 64), 512, 0, stream>>>(P0, WT, conv1_b, P1,
                                              nullptr, nullptr, 3, 1, 1, 1);
    // h2 = gelu(conv2(h1)) -> P0 flat + row LN-stats atomics
    gemm_8ph<<<dim3(4, 64), 512, 0, stream>>>(P1, WT + 3u * (1u << 20), conv2_b, P0,
                                              rowS, rowQ, 3, 1, 1, 0);
    // fused LN-transpose -> BTR bf16 [B,D,S]
    transposeLN<<<dim3(32, 64, 8), dim3(32, 8), 0, stream>>>(P0, rowS, rowQ,
                                                             ln_g, ln_b, BTR);
    // forward FFT (packed-bf16 half-spectrum) + complexity counts
    fft_fwd<<<BD_ROWS, 256, 0, stream>>>(BTR, Xs, counts);
    calc_n<<<1, 64, 0, stream>>>(counts, Ndev);
    // masked inverse FFT -> P1 bf16 [B,D,S]
    fft_inv<<<BD_ROWS, 256, 0, stream>>>(Xs, Ndev, P1);
    // [B,D,S] -> [B,S,D] bf16 -> P0 flat (x_ifft_raw)
    transpose_bb<<<dim3(64, 32, 8), dim3(32, 8), 0, stream>>>(P1, P0, D_DIM, S_LEN);
    // proj_out = x_ifft_raw @ proj_w + b -> P1 bf16 + row LN-stats atomics
    gemm_8ph<<<dim3(4, 64), 512, 0, stream>>>(P0, WT + 6u * (1u << 20), proj_b, P1,
                                              rowS2, rowQ2, 1, 0, 0, 0);
    // x_ifft = LN(proj_out) -> d_out + cos/l1 row stats
    ln_loss<<<R_ROWS, 256, 0, stream>>>(P1, ln_g, ln_b, out, rowS2, rowQ2, rowA, rowL1);
    // fused ph stats: masked interleaved-B 8-phase GEMM (rows s < N[b] only)
    phstats_8ph<<<dim3(8, 32), 512, 0, stream>>>(P1, WTI, ph_b, vg, c0,
                                                 rowS2, rowQ2, Ndev, Sxx, Stt, Sxt);
    final_loss<<<1, 1024, 0, stream>>>(rowA, rowL1, Sxx, Stt, Sxt, Ndev, out);
}